// Round 9
// baseline (199.950 us; speedup 1.0000x reference)
//
#include <hip/hip_runtime.h>
#include <stdint.h>

#define BB 2
#define TT 2048
#define EE 1024
#define HH 16
#define DD 64
#define MM (BB*TT)   // 4096 rows

typedef unsigned short u16;
typedef __attribute__((ext_vector_type(4))) float f32x4;
typedef __attribute__((ext_vector_type(8))) __bf16 bf16x8;
typedef __attribute__((ext_vector_type(8))) u16 u16x8;
typedef __attribute__((ext_vector_type(4))) u16 u16x4;

union FragU { u16x8 u; bf16x8 b; };
union BfU { __bf16 h; u16 u; };

__device__ __forceinline__ u16 f2bf(float f) {
  uint32_t u = __float_as_uint(f);
  u += 0x7fffu + ((u >> 16) & 1u);   // RNE (inputs are finite)
  return (u16)(u >> 16);
}

__device__ __forceinline__ u16x8 cvt8(f32x4 a, f32x4 b) {
  u16x8 o;
  o[0]=f2bf(a[0]); o[1]=f2bf(a[1]); o[2]=f2bf(a[2]); o[3]=f2bf(a[3]);
  o[4]=f2bf(b[0]); o[5]=f2bf(b[1]); o[6]=f2bf(b[2]); o[7]=f2bf(b[3]);
  return o;
}

// ---------------- weight transpose + convert: Wt[n][k] = bf16(W[k][n]) ----------------
__global__ __launch_bounds__(256) void wt_cvt4(const float* __restrict__ W0, const float* __restrict__ W1,
                                               const float* __restrict__ W2, const float* __restrict__ W3,
                                               u16* __restrict__ T0, u16* __restrict__ T1,
                                               u16* __restrict__ T2, u16* __restrict__ T3) {
  const float* W; u16* Tp;
  switch (blockIdx.z) {
    case 0: W = W0; Tp = T0; break;
    case 1: W = W1; Tp = T1; break;
    case 2: W = W2; Tp = T2; break;
    default: W = W3; Tp = T3; break;
  }
  int n0 = blockIdx.x * 64, k0 = blockIdx.y * 64;
  __shared__ alignas(16) float tile[64][65];
  int t = threadIdx.x;
#pragma unroll
  for (int i = 0; i < 16; ++i) {
    int idx = i*256 + t; int r = idx >> 6, c = idx & 63;
    tile[r][c] = W[(size_t)(k0 + r) * EE + n0 + c];
  }
  __syncthreads();
#pragma unroll
  for (int i = 0; i < 16; ++i) {
    int idx = i*256 + t; int rn = idx >> 6, ck = idx & 63;
    Tp[(size_t)(n0 + rn) * EE + k0 + ck] = f2bf(tile[ck][rn]);
  }
}

// ---------------- GEMM body: C[M][N] = (A @ Bt^T + bias) * oscale ----------------
// 64x128 tile, BK=64, 4 waves (2x2: 32-row x 64-col quadrants), 16x16x32 bf16 MFMA.
template <bool AF32, bool F32OUT>
__device__ __forceinline__ void gemm_body(const void* __restrict__ A, const u16* __restrict__ Bt,
                                          const float* __restrict__ bias0, const float* __restrict__ bias1,
                                          int nsplit, void* __restrict__ Cout,
                                          int N, int K, float oscale, int bm, int bn,
                                          u16 (*As)[72], u16 (*Bs)[72]) {
  const int t = threadIdx.x;
  const int lane = t & 63, wave = t >> 6;
  const int wr = wave >> 1, wc = wave & 1;

  f32x4 acc[2][4] = {};

  const int srow = t >> 3;            // 0..31
  const int scol = (t & 7) * 8;       // elem col 0..56
  const u16* Ag16 = (const u16*)A + (size_t)(bm * 64) * K;
  const float* Ag32 = (const float*)A + (size_t)(bm * 64) * K;
  const u16* Bg = Bt + (size_t)(bn * 128) * K;

  u16x8 ra[2], rb[4];
#pragma unroll
  for (int r = 0; r < 2; ++r) {
    if (AF32) {
      const float* p = Ag32 + (size_t)(r*32 + srow) * K + scol;
      ra[r] = cvt8(*(const f32x4*)p, *(const f32x4*)(p + 4));
    } else {
      ra[r] = *(const u16x8*)(Ag16 + (size_t)(r*32 + srow) * K + scol);
    }
  }
#pragma unroll
  for (int r = 0; r < 4; ++r)
    rb[r] = *(const u16x8*)(Bg + (size_t)(r*32 + srow) * K + scol);

  const int nk = K / 64;
  for (int kt = 0; kt < nk; ++kt) {
    __syncthreads();
#pragma unroll
    for (int r = 0; r < 2; ++r) *(u16x8*)&As[r*32 + srow][scol] = ra[r];
#pragma unroll
    for (int r = 0; r < 4; ++r) *(u16x8*)&Bs[r*32 + srow][scol] = rb[r];
    __syncthreads();
    if (kt + 1 < nk) {
      const int k0 = (kt + 1) * 64;
#pragma unroll
      for (int r = 0; r < 2; ++r) {
        if (AF32) {
          const float* p = Ag32 + (size_t)(r*32 + srow) * K + k0 + scol;
          ra[r] = cvt8(*(const f32x4*)p, *(const f32x4*)(p + 4));
        } else {
          ra[r] = *(const u16x8*)(Ag16 + (size_t)(r*32 + srow) * K + k0 + scol);
        }
      }
#pragma unroll
      for (int r = 0; r < 4; ++r)
        rb[r] = *(const u16x8*)(Bg + (size_t)(r*32 + srow) * K + k0 + scol);
    }
#pragma unroll
    for (int ks = 0; ks < 2; ++ks) {
      const int kc = ks*32 + ((lane >> 4) << 3);
      FragU af[2], bfr[4];
#pragma unroll
      for (int mi = 0; mi < 2; ++mi)
        af[mi].u = *(const u16x8*)&As[wr*32 + mi*16 + (lane & 15)][kc];
#pragma unroll
      for (int nj = 0; nj < 4; ++nj)
        bfr[nj].u = *(const u16x8*)&Bs[wc*64 + nj*16 + (lane & 15)][kc];
#pragma unroll
      for (int mi = 0; mi < 2; ++mi)
#pragma unroll
        for (int nj = 0; nj < 4; ++nj)
          acc[mi][nj] = __builtin_amdgcn_mfma_f32_16x16x32_bf16(af[mi].b, bfr[nj].b, acc[mi][nj], 0, 0, 0);
    }
  }

  // epilogue: bias + scale + store. C/D layout: col=lane&15, row=(lane>>4)*4+reg
  const int cbase = bn*128 + wc*64 + (lane & 15);
  const float* bp = (bn*128 < nsplit) ? bias0 : (bias1 - nsplit);
  float bv[4];
#pragma unroll
  for (int nj = 0; nj < 4; ++nj) bv[nj] = bp[cbase + nj*16];
#pragma unroll
  for (int mi = 0; mi < 2; ++mi) {
    int row0 = bm*64 + wr*32 + mi*16 + ((lane >> 4) << 2);
#pragma unroll
    for (int i = 0; i < 4; ++i) {
      if (F32OUT) {
        float* Cp = (float*)Cout + (size_t)(row0 + i) * N + cbase;
#pragma unroll
        for (int nj = 0; nj < 4; ++nj)
          Cp[nj*16] = (acc[mi][nj][i] + bv[nj]) * oscale;
      } else {
        u16* Cp = (u16*)Cout + (size_t)(row0 + i) * N + cbase;
#pragma unroll
        for (int nj = 0; nj < 4; ++nj)
          Cp[nj*16] = f2bf((acc[mi][nj][i] + bv[nj]) * oscale);
      }
    }
  }
}

// Fused Q + KV projection: grid (8+16, 64). bx<8 -> Q gemm, else KV gemm.
__global__ __launch_bounds__(256) void gemm_qkv(const float* __restrict__ x, const float* __restrict__ y,
                                                const u16* __restrict__ Wqt, const u16* __restrict__ Wkvt,
                                                const float* __restrict__ bq, const float* __restrict__ bk,
                                                const float* __restrict__ bv,
                                                u16* __restrict__ Qb, u16* __restrict__ KVb, float c1) {
  __shared__ alignas(16) u16 As[64][72];
  __shared__ alignas(16) u16 Bs[128][72];
  const int bx = blockIdx.x, bm = blockIdx.y;
  if (bx < 8)
    gemm_body<true, false>(x, Wqt, bq, bq, 1024, Qb, 1024, EE, c1, bm, bx, As, Bs);
  else
    gemm_body<true, false>(y, Wkvt, bk, bv, 1024, KVb, 2048, EE, 1.0f, bm, bx - 8, As, Bs);
}

// Output projection
__global__ __launch_bounds__(256) void gemm_o(const u16* __restrict__ Atb, const u16* __restrict__ Wot,
                                              const float* __restrict__ bo, float* __restrict__ out) {
  __shared__ alignas(16) u16 As[64][72];
  __shared__ alignas(16) u16 Bs[128][72];
  gemm_body<false, true>(Atb, Wot, bo, bo, 1024, out, 1024, EE, 1.0f, blockIdx.y, blockIdx.x, As, Bs);
}

// ---------------- V transpose: KV[b*T+t][1024 + h*64 + d] -> Vt[b][h][d][t] ----------------
__global__ __launch_bounds__(256) void transpose_v(const u16* __restrict__ KV, u16* __restrict__ Vt) {
  int tb = blockIdx.x, h = blockIdx.y, b = blockIdx.z;
  __shared__ alignas(16) u16 tile[64][66];
  int t = threadIdx.x;
  int t0 = tb * 64;
#pragma unroll
  for (int i = 0; i < 16; ++i) {
    int idx = i*256 + t; int r = idx >> 6, c = idx & 63;
    tile[r][c] = KV[(size_t)(b*TT + t0 + r) * 2048 + 1024 + h*DD + c];
  }
  __syncthreads();
#pragma unroll
  for (int i = 0; i < 16; ++i) {
    int idx = i*256 + t; int dd = idx >> 6, tt2 = idx & 63;
    Vt[((size_t)(b*HH + h) * DD + dd) * TT + t0 + tt2] = tile[tt2][dd];
  }
}

// ---------------- causal flash attention (split-KV, 8 waves, swapped-QK^T) ----------------
// Block = 512 thr = 8 waves over 64 q-rows: waves 0-3 (lo) compute even kv tiles,
// waves 4-7 (hi) odd kv tiles of the same rows; (m,l,O) partials merged via LDS at end.
// Grid = 1024 blocks, LPT-ordered (qt = 31-(i>>5)). Q pre-scaled by scale*log2(e).
__global__ __launch_bounds__(512, 8) void attn(const u16* __restrict__ Q, const u16* __restrict__ KV,
                                               const u16* __restrict__ Vt, u16* __restrict__ O) {
  const int i0 = blockIdx.x;
  const int qt = 31 - (i0 >> 5);
  const int bh = i0 & 31;
  const int b = bh >> 4, h = bh & 15;

  const int t = threadIdx.x, lane = t & 63, w = t >> 6;
  const int ws_ = w & 3;            // q sub-block 0..3
  const int hi = w >> 2;            // 0: even tiles, 1: odd tiles
  const int g = lane >> 4, c = lane & 15;
  __shared__ alignas(16) u16 Ks[2][64][72];
  __shared__ alignas(16) u16 Vs[2][64][72];

  const int qw0 = qt * 64 + ws_ * 16;         // 16 q-rows per wave

  // hoist Q fragments (B-operand): row qw0 + c, d = ks*32 + g*8 + 0..7
  FragU qf[2];
  const u16* Qbase = Q + ((size_t)(b*TT) + qw0) * EE + h*DD;
#pragma unroll
  for (int ks = 0; ks < 2; ++ks)
    qf[ks].u = *(const u16x8*)(Qbase + (size_t)c * EE + ks*32 + g*8);

  f32x4 oacc[4] = {};
  float l_part = 0.f;
  float m_run = -1e30f;

  const u16* Kbase = KV + (size_t)(b*TT) * 2048 + h*DD;     // K part: cols 0..1023
  const u16* Vtbase = Vt + (size_t)(b*HH + h) * DD * TT;

  const int nkv = qt + 1;
  const int npair = (nkv + 1) >> 1;

  // staging: 512 threads, one u16x8 per tile each (4 tiles/pair: K-even,V-even,K-odd,V-odd)
  const int srow = t >> 3;          // 0..63
  const int scol = (t & 7) * 8;     // u16 col

  u16x8 rk[2], rv[2];
  rk[0] = *(const u16x8*)(Kbase + (size_t)srow * 2048 + scol);
  rv[0] = *(const u16x8*)(Vtbase + (size_t)srow * TT + scol);
  if (1 < nkv) {
    rk[1] = *(const u16x8*)(Kbase + (size_t)(64 + srow) * 2048 + scol);
    rv[1] = *(const u16x8*)(Vtbase + (size_t)srow * TT + 64 + scol);
  }

  for (int jj = 0; jj < npair; ++jj) {
    const int j0 = 2*jj;
    __syncthreads();
    *(u16x8*)&Ks[0][srow][scol] = rk[0];
    *(u16x8*)&Vs[0][srow][scol] = rv[0];
    if (j0 + 1 < nkv) {
      *(u16x8*)&Ks[1][srow][scol] = rk[1];
      *(u16x8*)&Vs[1][srow][scol] = rv[1];
    }
    __syncthreads();
    if (jj + 1 < npair) {
      const int jn = 2*(jj + 1);
      rk[0] = *(const u16x8*)(Kbase + (size_t)(jn*64 + srow) * 2048 + scol);
      rv[0] = *(const u16x8*)(Vtbase + (size_t)srow * TT + jn*64 + scol);
      if (jn + 1 < nkv) {
        rk[1] = *(const u16x8*)(Kbase + (size_t)((jn+1)*64 + srow) * 2048 + scol);
        rv[1] = *(const u16x8*)(Vtbase + (size_t)srow * TT + (jn+1)*64 + scol);
      }
    }
    const int j = j0 + hi;
    const int kv0 = j * 64;
    if (j >= nkv || kv0 > qw0 + 15) continue;   // no unmasked cols for this wave

    // S^T = K Q^T: lane holds s[nj][r] = S[q = qw0+c][kv = kv0 + nj*16 + 4g + r]
    f32x4 s[4] = {};
    __builtin_amdgcn_s_setprio(1);
#pragma unroll
    for (int ks = 0; ks < 2; ++ks) {
      const int kc = ks*32 + g*8;
      FragU kf[4];
#pragma unroll
      for (int nj = 0; nj < 4; ++nj)
        kf[nj].u = *(const u16x8*)&Ks[hi][nj*16 + c][kc];
#pragma unroll
      for (int nj = 0; nj < 4; ++nj)
        s[nj] = __builtin_amdgcn_mfma_f32_16x16x32_bf16(kf[nj].b, qf[ks].b, s[nj], 0, 0, 0);
    }
    __builtin_amdgcn_s_setprio(0);

    const bool full = (kv0 + 63 <= qw0);
    const int q = qw0 + c;
    float vmax = -1e30f;
#pragma unroll
    for (int nj = 0; nj < 4; ++nj)
#pragma unroll
      for (int r = 0; r < 4; ++r) {
        float xv = s[nj][r];
        if (!full) {
          if (kv0 + nj*16 + 4*g + r > q) xv = -1e30f;
        }
        s[nj][r] = xv;
        vmax = fmaxf(vmax, xv);
      }

    // ballot-guarded defer-max: common path = 1 vote
    if (__any(vmax > m_run + 8.f)) {
      float vm = vmax;
      vm = fmaxf(vm, __shfl_xor(vm, 1));
      vm = fmaxf(vm, __shfl_xor(vm, 2));
      vm = fmaxf(vm, __shfl_xor(vm, 4));
      vm = fmaxf(vm, __shfl_xor(vm, 8));
      vm = fmaxf(vm, __shfl_xor(vm, 16));
      vm = fmaxf(vm, __shfl_xor(vm, 32));
      float f = exp2f(m_run - vm);   // 0 on first computed tile
      l_part *= f;
#pragma unroll
      for (int dj = 0; dj < 4; ++dj)
#pragma unroll
        for (int i = 0; i < 4; ++i) oacc[dj][i] *= f;
      m_run = vm;
    }

    // P = exp2(S - m), packed directly into PV A-fragments
    FragU pa[2];
    float psum = 0.f;
#pragma unroll
    for (int nj = 0; nj < 4; ++nj)
#pragma unroll
      for (int r = 0; r < 4; ++r) {
        float p = exp2f(s[nj][r] - m_run);
        psum += p;
        BfU cv; cv.h = (__bf16)p;
        pa[nj >> 1].u[(nj & 1) * 4 + r] = cv.u;
      }
    l_part += psum;

    // O += P @ V : B-operand from Vs rows (V^T), kv order matching the swapped layout
    __builtin_amdgcn_s_setprio(1);
#pragma unroll
    for (int ks = 0; ks < 2; ++ks) {
#pragma unroll
      for (int dj = 0; dj < 4; ++dj) {
        const u16* vrow = &Vs[hi][dj*16 + c][ks*32 + 4*g];
        u16x4 lo4 = *(const u16x4*)vrow;
        u16x4 hi4 = *(const u16x4*)(vrow + 16);
        FragU vf;
#pragma unroll
        for (int e = 0; e < 4; ++e) { vf.u[e] = lo4[e]; vf.u[4+e] = hi4[e]; }
        oacc[dj] = __builtin_amdgcn_mfma_f32_16x16x32_bf16(pa[ks].b, vf.b, oacc[dj], 0, 0, 0);
      }
    }
    __builtin_amdgcn_s_setprio(0);
  }

  // ---- merge lo/hi partials ----
  __syncthreads();
  // reduce l over the 4 lane-groups (same q-row set); lane c then holds l(row c)
  l_part += __shfl_xor(l_part, 16);
  l_part += __shfl_xor(l_part, 32);

  float* mO = (float*)&Ks[0][0][0];   // [4][16][66] f32 = 16.9 KB (fits in Ks, 18 KB)
  float* mL = (float*)&Vs[0][0][0];   // [4][16] l1 + [4] m1

  if (hi) {
#pragma unroll
    for (int i = 0; i < 4; ++i) {
      int row = 4*g + i;
#pragma unroll
      for (int dj = 0; dj < 4; ++dj)
        mO[((size_t)(ws_*16 + row))*66 + dj*16 + c] = oacc[dj][i];
    }
    if (lane < 16) mL[ws_*16 + lane] = l_part;
    if (lane == 0) mL[64 + ws_] = m_run;
  }
  __syncthreads();
  if (!hi) {
    float m1 = mL[64 + ws_];
    float l1 = mL[ws_*16 + c];
    float mN = fmaxf(m_run, m1);
    float f0 = exp2f(m_run - mN);   // wave-uniform
    float f1 = exp2f(m1 - mN);
    float lm = l_part * f0 + l1 * f1;
    u16* Ob = O + ((size_t)(b*TT) + qw0) * EE + h*DD;
#pragma unroll
    for (int i = 0; i < 4; ++i) {
      int row = 4*g + i;
      float li = __shfl(lm, row);   // lane 'row' holds c = row
      float inv = 1.f / li;
#pragma unroll
      for (int dj = 0; dj < 4; ++dj) {
        float o1 = mO[((size_t)(ws_*16 + row))*66 + dj*16 + c];
        Ob[(size_t)row * EE + dj*16 + c] = f2bf((oacc[dj][i] * f0 + o1 * f1) * inv);
      }
    }
  }
}

// ---------------- launch ----------------
extern "C" void kernel_launch(void* const* d_in, const int* in_sizes, int n_in,
                              void* d_out, int out_size, void* d_ws, size_t ws_size,
                              hipStream_t stream) {
  const float* x  = (const float*)d_in[0];
  const float* y  = (const float*)d_in[1];
  // d_in[2] = mask (tril causal; implemented analytically)
  const float* Wq = (const float*)d_in[3];
  const float* bq = (const float*)d_in[4];
  const float* Wk = (const float*)d_in[5];
  const float* bk = (const float*)d_in[6];
  const float* Wv = (const float*)d_in[7];
  const float* bv = (const float*)d_in[8];
  const float* Wo = (const float*)d_in[9];
  const float* bo = (const float*)d_in[10];

  if (ws_size < (size_t)50331648) return;  // need 48 MiB scratch

  char* ws = (char*)d_ws;
  u16* Wqt  = (u16*)(ws + 0);          // [1024][1024] bf16, 2 MiB
  u16* Wkvt = (u16*)(ws + 2097152);    // [2048][1024] bf16, 4 MiB ([Wk^T | Wv^T] rows)
  u16* Wot  = (u16*)(ws + 6291456);    // [1024][1024] bf16, 2 MiB
  u16* Qb   = (u16*)(ws + 8388608);    // [4096][1024] bf16, 8 MiB
  u16* KVb  = (u16*)(ws + 16777216);   // [4096][2048] bf16, 16 MiB ([K | V] cols)
  u16* Vtb  = (u16*)(ws + 33554432);   // [2][16][64][2048] bf16, 8 MiB
  u16* Atb  = (u16*)(ws + 41943040);   // [4096][1024] bf16, 8 MiB

  const float c1 = 0.125f * 1.44269504088896340736f;  // scale * log2(e), folded into Q

  wt_cvt4<<<dim3(16,16,4), 256, 0, stream>>>(Wq, Wk, Wv, Wo,
                                             Wqt, Wkvt, Wkvt + (size_t)1024*EE, Wot);
  gemm_qkv<<<dim3(24,64), 256, 0, stream>>>(x, y, Wqt, Wkvt, bq, bk, bv, Qb, KVb, c1);
  transpose_v<<<dim3(32,16,2), 256, 0, stream>>>(KVb, Vtb);
  attn<<<1024, 512, 0, stream>>>(Qb, KVb, Vtb, Atb);
  gemm_o<<<dim3(8,64), 256, 0, stream>>>(Atb, Wot, bo, (float*)d_out);
}

// Round 10
// 129.071 us; speedup vs baseline: 1.5491x; 1.5491x over previous
//
#include <hip/hip_runtime.h>
#include <stdint.h>

#define BB 2
#define TT 2048
#define EE 1024
#define HH 16
#define DD 64
#define MM (BB*TT)   // 4096 rows

typedef unsigned short u16;
typedef __attribute__((ext_vector_type(4))) float f32x4;
typedef __attribute__((ext_vector_type(8))) __bf16 bf16x8;
typedef __attribute__((ext_vector_type(8))) u16 u16x8;
typedef __attribute__((ext_vector_type(4))) u16 u16x4;

union FragU { u16x8 u; bf16x8 b; };
union BfU { __bf16 h; u16 u; };

__device__ __forceinline__ u16 f2bf(float f) {
  uint32_t u = __float_as_uint(f);
  u += 0x7fffu + ((u >> 16) & 1u);   // RNE (inputs are finite)
  return (u16)(u >> 16);
}

__device__ __forceinline__ u16x8 cvt8(f32x4 a, f32x4 b) {
  u16x8 o;
  o[0]=f2bf(a[0]); o[1]=f2bf(a[1]); o[2]=f2bf(a[2]); o[3]=f2bf(a[3]);
  o[4]=f2bf(b[0]); o[5]=f2bf(b[1]); o[6]=f2bf(b[2]); o[7]=f2bf(b[3]);
  return o;
}

// ---------------- weight transpose + convert: Wt[n][k] = bf16(W[k][n]) ----------------
__global__ __launch_bounds__(256) void wt_cvt4(const float* __restrict__ W0, const float* __restrict__ W1,
                                               const float* __restrict__ W2, const float* __restrict__ W3,
                                               u16* __restrict__ T0, u16* __restrict__ T1,
                                               u16* __restrict__ T2, u16* __restrict__ T3) {
  const float* W; u16* Tp;
  switch (blockIdx.z) {
    case 0: W = W0; Tp = T0; break;
    case 1: W = W1; Tp = T1; break;
    case 2: W = W2; Tp = T2; break;
    default: W = W3; Tp = T3; break;
  }
  int n0 = blockIdx.x * 64, k0 = blockIdx.y * 64;
  __shared__ alignas(16) float tile[64][65];
  int t = threadIdx.x;
#pragma unroll
  for (int i = 0; i < 16; ++i) {
    int idx = i*256 + t; int r = idx >> 6, c = idx & 63;
    tile[r][c] = W[(size_t)(k0 + r) * EE + n0 + c];
  }
  __syncthreads();
#pragma unroll
  for (int i = 0; i < 16; ++i) {
    int idx = i*256 + t; int rn = idx >> 6, ck = idx & 63;
    Tp[(size_t)(n0 + rn) * EE + k0 + ck] = f2bf(tile[ck][rn]);
  }
}

// ---------------- GEMM body: C[M][N] = (A @ Bt^T + bias) * oscale ----------------
// 64x128 tile, BK=64, 4 waves (2x2: 32-row x 64-col quadrants), 16x16x32 bf16 MFMA.
template <bool AF32, bool F32OUT>
__device__ __forceinline__ void gemm_body(const void* __restrict__ A, const u16* __restrict__ Bt,
                                          const float* __restrict__ bias0, const float* __restrict__ bias1,
                                          int nsplit, void* __restrict__ Cout,
                                          int N, int K, float oscale, int bm, int bn,
                                          u16 (*As)[72], u16 (*Bs)[72]) {
  const int t = threadIdx.x;
  const int lane = t & 63, wave = t >> 6;
  const int wr = wave >> 1, wc = wave & 1;

  f32x4 acc[2][4] = {};

  const int srow = t >> 3;            // 0..31
  const int scol = (t & 7) * 8;       // elem col 0..56
  const u16* Ag16 = (const u16*)A + (size_t)(bm * 64) * K;
  const float* Ag32 = (const float*)A + (size_t)(bm * 64) * K;
  const u16* Bg = Bt + (size_t)(bn * 128) * K;

  u16x8 ra[2], rb[4];
#pragma unroll
  for (int r = 0; r < 2; ++r) {
    if (AF32) {
      const float* p = Ag32 + (size_t)(r*32 + srow) * K + scol;
      ra[r] = cvt8(*(const f32x4*)p, *(const f32x4*)(p + 4));
    } else {
      ra[r] = *(const u16x8*)(Ag16 + (size_t)(r*32 + srow) * K + scol);
    }
  }
#pragma unroll
  for (int r = 0; r < 4; ++r)
    rb[r] = *(const u16x8*)(Bg + (size_t)(r*32 + srow) * K + scol);

  const int nk = K / 64;
  for (int kt = 0; kt < nk; ++kt) {
    __syncthreads();
#pragma unroll
    for (int r = 0; r < 2; ++r) *(u16x8*)&As[r*32 + srow][scol] = ra[r];
#pragma unroll
    for (int r = 0; r < 4; ++r) *(u16x8*)&Bs[r*32 + srow][scol] = rb[r];
    __syncthreads();
    if (kt + 1 < nk) {
      const int k0 = (kt + 1) * 64;
#pragma unroll
      for (int r = 0; r < 2; ++r) {
        if (AF32) {
          const float* p = Ag32 + (size_t)(r*32 + srow) * K + k0 + scol;
          ra[r] = cvt8(*(const f32x4*)p, *(const f32x4*)(p + 4));
        } else {
          ra[r] = *(const u16x8*)(Ag16 + (size_t)(r*32 + srow) * K + k0 + scol);
        }
      }
#pragma unroll
      for (int r = 0; r < 4; ++r)
        rb[r] = *(const u16x8*)(Bg + (size_t)(r*32 + srow) * K + k0 + scol);
    }
#pragma unroll
    for (int ks = 0; ks < 2; ++ks) {
      const int kc = ks*32 + ((lane >> 4) << 3);
      FragU af[2], bfr[4];
#pragma unroll
      for (int mi = 0; mi < 2; ++mi)
        af[mi].u = *(const u16x8*)&As[wr*32 + mi*16 + (lane & 15)][kc];
#pragma unroll
      for (int nj = 0; nj < 4; ++nj)
        bfr[nj].u = *(const u16x8*)&Bs[wc*64 + nj*16 + (lane & 15)][kc];
#pragma unroll
      for (int mi = 0; mi < 2; ++mi)
#pragma unroll
        for (int nj = 0; nj < 4; ++nj)
          acc[mi][nj] = __builtin_amdgcn_mfma_f32_16x16x32_bf16(af[mi].b, bfr[nj].b, acc[mi][nj], 0, 0, 0);
    }
  }

  // epilogue: bias + scale + store. C/D layout: col=lane&15, row=(lane>>4)*4+reg
  const int cbase = bn*128 + wc*64 + (lane & 15);
  const float* bp = (bn*128 < nsplit) ? bias0 : (bias1 - nsplit);
  float bv[4];
#pragma unroll
  for (int nj = 0; nj < 4; ++nj) bv[nj] = bp[cbase + nj*16];
#pragma unroll
  for (int mi = 0; mi < 2; ++mi) {
    int row0 = bm*64 + wr*32 + mi*16 + ((lane >> 4) << 2);
#pragma unroll
    for (int i = 0; i < 4; ++i) {
      if (F32OUT) {
        float* Cp = (float*)Cout + (size_t)(row0 + i) * N + cbase;
#pragma unroll
        for (int nj = 0; nj < 4; ++nj)
          Cp[nj*16] = (acc[mi][nj][i] + bv[nj]) * oscale;
      } else {
        u16* Cp = (u16*)Cout + (size_t)(row0 + i) * N + cbase;
#pragma unroll
        for (int nj = 0; nj < 4; ++nj)
          Cp[nj*16] = f2bf((acc[mi][nj][i] + bv[nj]) * oscale);
      }
    }
  }
}

// Fused Q + KV projection: grid (8+16, 64). bx<8 -> Q gemm, else KV gemm.
__global__ __launch_bounds__(256) void gemm_qkv(const float* __restrict__ x, const float* __restrict__ y,
                                                const u16* __restrict__ Wqt, const u16* __restrict__ Wkvt,
                                                const float* __restrict__ bq, const float* __restrict__ bk,
                                                const float* __restrict__ bv,
                                                u16* __restrict__ Qb, u16* __restrict__ KVb, float c1) {
  __shared__ alignas(16) u16 As[64][72];
  __shared__ alignas(16) u16 Bs[128][72];
  const int bx = blockIdx.x, bm = blockIdx.y;
  if (bx < 8)
    gemm_body<true, false>(x, Wqt, bq, bq, 1024, Qb, 1024, EE, c1, bm, bx, As, Bs);
  else
    gemm_body<true, false>(y, Wkvt, bk, bv, 1024, KVb, 2048, EE, 1.0f, bm, bx - 8, As, Bs);
}

// Output projection
__global__ __launch_bounds__(256) void gemm_o(const u16* __restrict__ Atb, const u16* __restrict__ Wot,
                                              const float* __restrict__ bo, float* __restrict__ out) {
  __shared__ alignas(16) u16 As[64][72];
  __shared__ alignas(16) u16 Bs[128][72];
  gemm_body<false, true>(Atb, Wot, bo, bo, 1024, out, 1024, EE, 1.0f, blockIdx.y, blockIdx.x, As, Bs);
}

// ---------------- V transpose: KV[b*T+t][1024 + h*64 + d] -> Vt[b][h][d][t] ----------------
__global__ __launch_bounds__(256) void transpose_v(const u16* __restrict__ KV, u16* __restrict__ Vt) {
  int tb = blockIdx.x, h = blockIdx.y, b = blockIdx.z;
  __shared__ alignas(16) u16 tile[64][66];
  int t = threadIdx.x;
  int t0 = tb * 64;
#pragma unroll
  for (int i = 0; i < 16; ++i) {
    int idx = i*256 + t; int r = idx >> 6, c = idx & 63;
    tile[r][c] = KV[(size_t)(b*TT + t0 + r) * 2048 + 1024 + h*DD + c];
  }
  __syncthreads();
#pragma unroll
  for (int i = 0; i < 16; ++i) {
    int idx = i*256 + t; int dd = idx >> 6, tt2 = idx & 63;
    Vt[((size_t)(b*HH + h) * DD + dd) * TT + t0 + tt2] = tile[tt2][dd];
  }
}

// ---------------- causal flash attention (split-KV, 8 waves, swapped-QK^T) ----------------
// Block = 512 thr = 8 waves over 64 q-rows: waves 0-3 (lo) compute even kv tiles,
// waves 4-7 (hi) odd kv tiles of the same rows; (m,l,O) partials merged via LDS at end.
// Grid = 1024 blocks, LPT-ordered (qt = 31-(i>>5)). Q pre-scaled by scale*log2(e).
// __launch_bounds__(512, 4): 128-VGPR budget -> no spill (round-9's (512,8) forced
// 64-VGPR and spilled: VGPR=32, FETCH 151MB).
__global__ __launch_bounds__(512, 4) void attn(const u16* __restrict__ Q, const u16* __restrict__ KV,
                                               const u16* __restrict__ Vt, u16* __restrict__ O) {
  const int i0 = blockIdx.x;
  const int qt = 31 - (i0 >> 5);
  const int bh = i0 & 31;
  const int b = bh >> 4, h = bh & 15;

  const int t = threadIdx.x, lane = t & 63, w = t >> 6;
  const int ws_ = w & 3;            // q sub-block 0..3
  const int hi = w >> 2;            // 0: even tiles, 1: odd tiles
  const int g = lane >> 4, c = lane & 15;
  __shared__ alignas(16) u16 Ks[2][64][72];
  __shared__ alignas(16) u16 Vs[2][64][72];

  const int qw0 = qt * 64 + ws_ * 16;         // 16 q-rows per wave

  // hoist Q fragments (B-operand): row qw0 + c, d = ks*32 + g*8 + 0..7
  FragU qf[2];
  const u16* Qbase = Q + ((size_t)(b*TT) + qw0) * EE + h*DD;
#pragma unroll
  for (int ks = 0; ks < 2; ++ks)
    qf[ks].u = *(const u16x8*)(Qbase + (size_t)c * EE + ks*32 + g*8);

  f32x4 oacc[4] = {};
  float l_part = 0.f;
  float m_run = -1e30f;

  const u16* Kbase = KV + (size_t)(b*TT) * 2048 + h*DD;     // K part: cols 0..1023
  const u16* Vtbase = Vt + (size_t)(b*HH + h) * DD * TT;

  const int nkv = qt + 1;
  const int npair = (nkv + 1) >> 1;

  // staging: 512 threads, one u16x8 per tile each (4 tiles/pair: K-even,V-even,K-odd,V-odd)
  const int srow = t >> 3;          // 0..63
  const int scol = (t & 7) * 8;     // u16 col

  u16x8 rk[2], rv[2];
  rk[0] = *(const u16x8*)(Kbase + (size_t)srow * 2048 + scol);
  rv[0] = *(const u16x8*)(Vtbase + (size_t)srow * TT + scol);
  if (1 < nkv) {
    rk[1] = *(const u16x8*)(Kbase + (size_t)(64 + srow) * 2048 + scol);
    rv[1] = *(const u16x8*)(Vtbase + (size_t)srow * TT + 64 + scol);
  }

  for (int jj = 0; jj < npair; ++jj) {
    const int j0 = 2*jj;
    __syncthreads();
    *(u16x8*)&Ks[0][srow][scol] = rk[0];
    *(u16x8*)&Vs[0][srow][scol] = rv[0];
    if (j0 + 1 < nkv) {
      *(u16x8*)&Ks[1][srow][scol] = rk[1];
      *(u16x8*)&Vs[1][srow][scol] = rv[1];
    }
    __syncthreads();
    if (jj + 1 < npair) {
      const int jn = 2*(jj + 1);
      rk[0] = *(const u16x8*)(Kbase + (size_t)(jn*64 + srow) * 2048 + scol);
      rv[0] = *(const u16x8*)(Vtbase + (size_t)srow * TT + jn*64 + scol);
      if (jn + 1 < nkv) {
        rk[1] = *(const u16x8*)(Kbase + (size_t)((jn+1)*64 + srow) * 2048 + scol);
        rv[1] = *(const u16x8*)(Vtbase + (size_t)srow * TT + (jn+1)*64 + scol);
      }
    }
    const int j = j0 + hi;
    const int kv0 = j * 64;
    if (j >= nkv || kv0 > qw0 + 15) continue;   // no unmasked cols for this wave

    // S^T = K Q^T: lane holds s[nj][r] = S[q = qw0+c][kv = kv0 + nj*16 + 4g + r]
    f32x4 s[4] = {};
    __builtin_amdgcn_s_setprio(1);
#pragma unroll
    for (int ks = 0; ks < 2; ++ks) {
      const int kc = ks*32 + g*8;
      FragU kf[4];
#pragma unroll
      for (int nj = 0; nj < 4; ++nj)
        kf[nj].u = *(const u16x8*)&Ks[hi][nj*16 + c][kc];
#pragma unroll
      for (int nj = 0; nj < 4; ++nj)
        s[nj] = __builtin_amdgcn_mfma_f32_16x16x32_bf16(kf[nj].b, qf[ks].b, s[nj], 0, 0, 0);
    }
    __builtin_amdgcn_s_setprio(0);

    const bool full = (kv0 + 63 <= qw0);
    const int q = qw0 + c;
    float vmax = -1e30f;
#pragma unroll
    for (int nj = 0; nj < 4; ++nj)
#pragma unroll
      for (int r = 0; r < 4; ++r) {
        float xv = s[nj][r];
        if (!full) {
          if (kv0 + nj*16 + 4*g + r > q) xv = -1e30f;
        }
        s[nj][r] = xv;
        vmax = fmaxf(vmax, xv);
      }

    // ballot-guarded defer-max: common path = 1 vote
    if (__any(vmax > m_run + 8.f)) {
      float vm = vmax;
      vm = fmaxf(vm, __shfl_xor(vm, 1));
      vm = fmaxf(vm, __shfl_xor(vm, 2));
      vm = fmaxf(vm, __shfl_xor(vm, 4));
      vm = fmaxf(vm, __shfl_xor(vm, 8));
      vm = fmaxf(vm, __shfl_xor(vm, 16));
      vm = fmaxf(vm, __shfl_xor(vm, 32));
      float f = exp2f(m_run - vm);   // 0 on first computed tile
      l_part *= f;
#pragma unroll
      for (int dj = 0; dj < 4; ++dj)
#pragma unroll
        for (int i = 0; i < 4; ++i) oacc[dj][i] *= f;
      m_run = vm;
    }

    // P = exp2(S - m), packed directly into PV A-fragments
    FragU pa[2];
    float psum = 0.f;
#pragma unroll
    for (int nj = 0; nj < 4; ++nj)
#pragma unroll
      for (int r = 0; r < 4; ++r) {
        float p = exp2f(s[nj][r] - m_run);
        psum += p;
        BfU cv; cv.h = (__bf16)p;
        pa[nj >> 1].u[(nj & 1) * 4 + r] = cv.u;
      }
    l_part += psum;

    // O += P @ V : B-operand from Vs rows (V^T), kv order matching the swapped layout
    __builtin_amdgcn_s_setprio(1);
#pragma unroll
    for (int ks = 0; ks < 2; ++ks) {
#pragma unroll
      for (int dj = 0; dj < 4; ++dj) {
        const u16* vrow = &Vs[hi][dj*16 + c][ks*32 + 4*g];
        u16x4 lo4 = *(const u16x4*)vrow;
        u16x4 hi4 = *(const u16x4*)(vrow + 16);
        FragU vf;
#pragma unroll
        for (int e = 0; e < 4; ++e) { vf.u[e] = lo4[e]; vf.u[4+e] = hi4[e]; }
        oacc[dj] = __builtin_amdgcn_mfma_f32_16x16x32_bf16(pa[ks].b, vf.b, oacc[dj], 0, 0, 0);
      }
    }
    __builtin_amdgcn_s_setprio(0);
  }

  // ---- merge lo/hi partials ----
  __syncthreads();
  // reduce l over the 4 lane-groups (same q-row set); lane c then holds l(row c)
  l_part += __shfl_xor(l_part, 16);
  l_part += __shfl_xor(l_part, 32);

  float* mO = (float*)&Ks[0][0][0];   // [4][16][66] f32 = 16.9 KB (fits in Ks, 18 KB)
  float* mL = (float*)&Vs[0][0][0];   // [4][16] l1 + [4] m1

  if (hi) {
#pragma unroll
    for (int i = 0; i < 4; ++i) {
      int row = 4*g + i;
#pragma unroll
      for (int dj = 0; dj < 4; ++dj)
        mO[((size_t)(ws_*16 + row))*66 + dj*16 + c] = oacc[dj][i];
    }
    if (lane < 16) mL[ws_*16 + lane] = l_part;
    if (lane == 0) mL[64 + ws_] = m_run;
  }
  __syncthreads();
  if (!hi) {
    float m1 = mL[64 + ws_];
    float l1 = mL[ws_*16 + c];
    float mN = fmaxf(m_run, m1);
    float f0 = exp2f(m_run - mN);   // wave-uniform
    float f1 = exp2f(m1 - mN);
    float lm = l_part * f0 + l1 * f1;
    u16* Ob = O + ((size_t)(b*TT) + qw0) * EE + h*DD;
#pragma unroll
    for (int i = 0; i < 4; ++i) {
      int row = 4*g + i;
      float li = __shfl(lm, row);   // lane 'row' holds c = row
      float inv = 1.f / li;
#pragma unroll
      for (int dj = 0; dj < 4; ++dj) {
        float o1 = mO[((size_t)(ws_*16 + row))*66 + dj*16 + c];
        Ob[(size_t)row * EE + dj*16 + c] = f2bf((oacc[dj][i] * f0 + o1 * f1) * inv);
      }
    }
  }
}

// ---------------- launch ----------------
extern "C" void kernel_launch(void* const* d_in, const int* in_sizes, int n_in,
                              void* d_out, int out_size, void* d_ws, size_t ws_size,
                              hipStream_t stream) {
  const float* x  = (const float*)d_in[0];
  const float* y  = (const float*)d_in[1];
  // d_in[2] = mask (tril causal; implemented analytically)
  const float* Wq = (const float*)d_in[3];
  const float* bq = (const float*)d_in[4];
  const float* Wk = (const float*)d_in[5];
  const float* bk = (const float*)d_in[6];
  const float* Wv = (const float*)d_in[7];
  const float* bv = (const float*)d_in[8];
  const float* Wo = (const float*)d_in[9];
  const float* bo = (const float*)d_in[10];

  if (ws_size < (size_t)50331648) return;  // need 48 MiB scratch

  char* ws = (char*)d_ws;
  u16* Wqt  = (u16*)(ws + 0);          // [1024][1024] bf16, 2 MiB
  u16* Wkvt = (u16*)(ws + 2097152);    // [2048][1024] bf16, 4 MiB ([Wk^T | Wv^T] rows)
  u16* Wot  = (u16*)(ws + 6291456);    // [1024][1024] bf16, 2 MiB
  u16* Qb   = (u16*)(ws + 8388608);    // [4096][1024] bf16, 8 MiB
  u16* KVb  = (u16*)(ws + 16777216);   // [4096][2048] bf16, 16 MiB ([K | V] cols)
  u16* Vtb  = (u16*)(ws + 33554432);   // [2][16][64][2048] bf16, 8 MiB
  u16* Atb  = (u16*)(ws + 41943040);   // [4096][1024] bf16, 8 MiB

  const float c1 = 0.125f * 1.44269504088896340736f;  // scale * log2(e), folded into Q

  wt_cvt4<<<dim3(16,16,4), 256, 0, stream>>>(Wq, Wk, Wv, Wo,
                                             Wqt, Wkvt, Wkvt + (size_t)1024*EE, Wot);
  gemm_qkv<<<dim3(24,64), 256, 0, stream>>>(x, y, Wqt, Wkvt, bq, bk, bv, Qb, KVb, c1);
  transpose_v<<<dim3(32,16,2), 256, 0, stream>>>(KVb, Vtb);
  attn<<<1024, 512, 0, stream>>>(Qb, KVb, Vtb, Atb);
  gemm_o<<<dim3(8,64), 256, 0, stream>>>(Atb, Wot, bo, (float*)d_out);
}

// Round 11
// 127.228 us; speedup vs baseline: 1.5716x; 1.0145x over previous
//
#include <hip/hip_runtime.h>
#include <stdint.h>

#define BB 2
#define TT 2048
#define EE 1024
#define HH 16
#define DD 64
#define MM (BB*TT)   // 4096 rows

typedef unsigned short u16;
typedef __attribute__((ext_vector_type(4))) float f32x4;
typedef __attribute__((ext_vector_type(8))) __bf16 bf16x8;
typedef __attribute__((ext_vector_type(8))) u16 u16x8;
typedef __attribute__((ext_vector_type(4))) u16 u16x4;

union FragU { u16x8 u; bf16x8 b; };
union BfU { __bf16 h; u16 u; };

__device__ __forceinline__ u16 f2bf(float f) {
  uint32_t u = __float_as_uint(f);
  u += 0x7fffu + ((u >> 16) & 1u);   // RNE (inputs are finite)
  return (u16)(u >> 16);
}

// ---------------- f32 -> bf16 convert: x (blocks 0..2047) then y ----------------
__global__ __launch_bounds__(256) void cvt_xy(const float* __restrict__ x, const float* __restrict__ y,
                                              u16* __restrict__ xb, u16* __restrict__ yb) {
  int bi = blockIdx.x;
  const float* src = (bi < 2048) ? x : y;
  u16* dst = (bi < 2048) ? xb : yb;
  int i = (bi & 2047) * 256 + threadIdx.x;
  const f32x4* s4 = (const f32x4*)src;
  f32x4 a = s4[2*i], b = s4[2*i+1];
  u16x8 o;
  o[0]=f2bf(a[0]); o[1]=f2bf(a[1]); o[2]=f2bf(a[2]); o[3]=f2bf(a[3]);
  o[4]=f2bf(b[0]); o[5]=f2bf(b[1]); o[6]=f2bf(b[2]); o[7]=f2bf(b[3]);
  ((u16x8*)dst)[i] = o;
}

// ---------------- weight transpose + convert: Wt[n][k] = bf16(W[k][n]) ----------------
__global__ __launch_bounds__(256) void wt_cvt4(const float* __restrict__ W0, const float* __restrict__ W1,
                                               const float* __restrict__ W2, const float* __restrict__ W3,
                                               u16* __restrict__ T0, u16* __restrict__ T1,
                                               u16* __restrict__ T2, u16* __restrict__ T3) {
  const float* W; u16* Tp;
  switch (blockIdx.z) {
    case 0: W = W0; Tp = T0; break;
    case 1: W = W1; Tp = T1; break;
    case 2: W = W2; Tp = T2; break;
    default: W = W3; Tp = T3; break;
  }
  int n0 = blockIdx.x * 64, k0 = blockIdx.y * 64;
  __shared__ alignas(16) float tile[64][65];
  int t = threadIdx.x;
#pragma unroll
  for (int i = 0; i < 16; ++i) {
    int idx = i*256 + t; int r = idx >> 6, c = idx & 63;
    tile[r][c] = W[(size_t)(k0 + r) * EE + n0 + c];
  }
  __syncthreads();
#pragma unroll
  for (int i = 0; i < 16; ++i) {
    int idx = i*256 + t; int rn = idx >> 6, ck = idx & 63;
    Tp[(size_t)(n0 + rn) * EE + k0 + ck] = f2bf(tile[ck][rn]);
  }
}

// ---------------- GEMM body: C[M][N] = (A @ Bt^T + bias) * oscale ----------------
// 64x128 tile, BK=64, 4 waves (2x2: 32-row x 64-col quadrants), 16x16x32 bf16 MFMA.
template <bool F32OUT>
__device__ __forceinline__ void gemm_body(const u16* __restrict__ A, const u16* __restrict__ Bt,
                                          const float* __restrict__ bias0, const float* __restrict__ bias1,
                                          int nsplit, void* __restrict__ Cout,
                                          int N, int K, float oscale, int bm, int bn,
                                          u16 (*As)[72], u16 (*Bs)[72]) {
  const int t = threadIdx.x;
  const int lane = t & 63, wave = t >> 6;
  const int wr = wave >> 1, wc = wave & 1;

  f32x4 acc[2][4] = {};

  const int srow = t >> 3;            // 0..31
  const int scol = (t & 7) * 8;       // elem col 0..56
  const u16* Ag = A + (size_t)(bm * 64) * K;
  const u16* Bg = Bt + (size_t)(bn * 128) * K;

  u16x8 ra[2], rb[4];
#pragma unroll
  for (int r = 0; r < 2; ++r)
    ra[r] = *(const u16x8*)(Ag + (size_t)(r*32 + srow) * K + scol);
#pragma unroll
  for (int r = 0; r < 4; ++r)
    rb[r] = *(const u16x8*)(Bg + (size_t)(r*32 + srow) * K + scol);

  const int nk = K / 64;
  for (int kt = 0; kt < nk; ++kt) {
    __syncthreads();
#pragma unroll
    for (int r = 0; r < 2; ++r) *(u16x8*)&As[r*32 + srow][scol] = ra[r];
#pragma unroll
    for (int r = 0; r < 4; ++r) *(u16x8*)&Bs[r*32 + srow][scol] = rb[r];
    __syncthreads();
    if (kt + 1 < nk) {
      const int k0 = (kt + 1) * 64;
#pragma unroll
      for (int r = 0; r < 2; ++r)
        ra[r] = *(const u16x8*)(Ag + (size_t)(r*32 + srow) * K + k0 + scol);
#pragma unroll
      for (int r = 0; r < 4; ++r)
        rb[r] = *(const u16x8*)(Bg + (size_t)(r*32 + srow) * K + k0 + scol);
    }
#pragma unroll
    for (int ks = 0; ks < 2; ++ks) {
      const int kc = ks*32 + ((lane >> 4) << 3);
      FragU af[2], bfr[4];
#pragma unroll
      for (int mi = 0; mi < 2; ++mi)
        af[mi].u = *(const u16x8*)&As[wr*32 + mi*16 + (lane & 15)][kc];
#pragma unroll
      for (int nj = 0; nj < 4; ++nj)
        bfr[nj].u = *(const u16x8*)&Bs[wc*64 + nj*16 + (lane & 15)][kc];
#pragma unroll
      for (int mi = 0; mi < 2; ++mi)
#pragma unroll
        for (int nj = 0; nj < 4; ++nj)
          acc[mi][nj] = __builtin_amdgcn_mfma_f32_16x16x32_bf16(af[mi].b, bfr[nj].b, acc[mi][nj], 0, 0, 0);
    }
  }

  // epilogue: bias + scale + store. C/D layout: col=lane&15, row=(lane>>4)*4+reg
  const int cbase = bn*128 + wc*64 + (lane & 15);
  const float* bp = (bn*128 < nsplit) ? bias0 : (bias1 - nsplit);
  float bv[4];
#pragma unroll
  for (int nj = 0; nj < 4; ++nj) bv[nj] = bp[cbase + nj*16];
#pragma unroll
  for (int mi = 0; mi < 2; ++mi) {
    int row0 = bm*64 + wr*32 + mi*16 + ((lane >> 4) << 2);
#pragma unroll
    for (int i = 0; i < 4; ++i) {
      if (F32OUT) {
        float* Cp = (float*)Cout + (size_t)(row0 + i) * N + cbase;
#pragma unroll
        for (int nj = 0; nj < 4; ++nj)
          Cp[nj*16] = (acc[mi][nj][i] + bv[nj]) * oscale;
      } else {
        u16* Cp = (u16*)Cout + (size_t)(row0 + i) * N + cbase;
#pragma unroll
        for (int nj = 0; nj < 4; ++nj)
          Cp[nj*16] = f2bf((acc[mi][nj][i] + bv[nj]) * oscale);
      }
    }
  }
}

// Fused Q + KV projection: flat grid 1536, XCD chunk-swizzled so the 24 blocks
// sharing an A-panel (one bm) land on one XCD (1536 % 8 == 0 -> bijective).
__global__ __launch_bounds__(256) void gemm_qkv(const u16* __restrict__ xb, const u16* __restrict__ yb,
                                                const u16* __restrict__ Wqt, const u16* __restrict__ Wkvt,
                                                const float* __restrict__ bq, const float* __restrict__ bk,
                                                const float* __restrict__ bv,
                                                u16* __restrict__ Qb, u16* __restrict__ KVb, float c1) {
  __shared__ alignas(16) u16 As[64][72];
  __shared__ alignas(16) u16 Bs[128][72];
  const int i = blockIdx.x;
  const int l = (i & 7) * 192 + (i >> 3);   // XCD chunk swizzle
  const int bm = l / 24, bx = l % 24;
  if (bx < 8)
    gemm_body<false>(xb, Wqt, bq, bq, 1024, Qb, 1024, EE, c1, bm, bx, As, Bs);
  else
    gemm_body<false>(yb, Wkvt, bk, bv, 1024, KVb, 2048, EE, 1.0f, bm, bx - 8, As, Bs);
}

// Output projection: flat grid 512, XCD chunk-swizzled (8 bm-groups per XCD).
__global__ __launch_bounds__(256) void gemm_o(const u16* __restrict__ Atb, const u16* __restrict__ Wot,
                                              const float* __restrict__ bo, float* __restrict__ out) {
  __shared__ alignas(16) u16 As[64][72];
  __shared__ alignas(16) u16 Bs[128][72];
  const int i = blockIdx.x;
  const int l = (i & 7) * 64 + (i >> 3);
  const int bm = l / 8, bn = l % 8;
  gemm_body<true>(Atb, Wot, bo, bo, 1024, out, 1024, EE, 1.0f, bm, bn, As, Bs);
}

// ---------------- V transpose: KV[b*T+t][1024 + h*64 + d] -> Vt[b][h][d][t] ----------------
__global__ __launch_bounds__(256) void transpose_v(const u16* __restrict__ KV, u16* __restrict__ Vt) {
  int tb = blockIdx.x, h = blockIdx.y, b = blockIdx.z;
  __shared__ alignas(16) u16 tile[64][66];
  int t = threadIdx.x;
  int t0 = tb * 64;
#pragma unroll
  for (int i = 0; i < 16; ++i) {
    int idx = i*256 + t; int r = idx >> 6, c = idx & 63;
    tile[r][c] = KV[(size_t)(b*TT + t0 + r) * 2048 + 1024 + h*DD + c];
  }
  __syncthreads();
#pragma unroll
  for (int i = 0; i < 16; ++i) {
    int idx = i*256 + t; int dd = idx >> 6, tt2 = idx & 63;
    Vt[((size_t)(b*HH + h) * DD + dd) * TT + t0 + tt2] = tile[tt2][dd];
  }
}

// ---------------- causal flash attention (split-KV, 8 waves, swapped-QK^T) ----------------
// Block = 512 thr = 8 waves over 64 q-rows: waves 0-3 (lo) compute even kv tiles,
// waves 4-7 (hi) odd kv tiles of the same rows; (m,l,O) partials merged via LDS at end.
// Grid = 1024 blocks, LPT-ordered (qt = 31-(i>>5)). Q pre-scaled by scale*log2(e).
// __launch_bounds__(512, 4): 128-VGPR budget -> no spill.
__global__ __launch_bounds__(512, 4) void attn(const u16* __restrict__ Q, const u16* __restrict__ KV,
                                               const u16* __restrict__ Vt, u16* __restrict__ O) {
  const int i0 = blockIdx.x;
  const int qt = 31 - (i0 >> 5);
  const int bh = i0 & 31;
  const int b = bh >> 4, h = bh & 15;

  const int t = threadIdx.x, lane = t & 63, w = t >> 6;
  const int ws_ = w & 3;            // q sub-block 0..3
  const int hi = w >> 2;            // 0: even tiles, 1: odd tiles
  const int g = lane >> 4, c = lane & 15;
  __shared__ alignas(16) u16 Ks[2][64][72];
  __shared__ alignas(16) u16 Vs[2][64][72];

  const int qw0 = qt * 64 + ws_ * 16;         // 16 q-rows per wave

  // hoist Q fragments (B-operand): row qw0 + c, d = ks*32 + g*8 + 0..7
  FragU qf[2];
  const u16* Qbase = Q + ((size_t)(b*TT) + qw0) * EE + h*DD;
#pragma unroll
  for (int ks = 0; ks < 2; ++ks)
    qf[ks].u = *(const u16x8*)(Qbase + (size_t)c * EE + ks*32 + g*8);

  f32x4 oacc[4] = {};
  float l_part = 0.f;
  float m_run = -1e30f;

  const u16* Kbase = KV + (size_t)(b*TT) * 2048 + h*DD;     // K part: cols 0..1023
  const u16* Vtbase = Vt + (size_t)(b*HH + h) * DD * TT;

  const int nkv = qt + 1;
  const int npair = (nkv + 1) >> 1;

  // staging: 512 threads, one u16x8 per tile each (4 tiles/pair: K-even,V-even,K-odd,V-odd)
  const int srow = t >> 3;          // 0..63
  const int scol = (t & 7) * 8;     // u16 col

  u16x8 rk[2], rv[2];
  rk[0] = *(const u16x8*)(Kbase + (size_t)srow * 2048 + scol);
  rv[0] = *(const u16x8*)(Vtbase + (size_t)srow * TT + scol);
  if (1 < nkv) {
    rk[1] = *(const u16x8*)(Kbase + (size_t)(64 + srow) * 2048 + scol);
    rv[1] = *(const u16x8*)(Vtbase + (size_t)srow * TT + 64 + scol);
  }

  for (int jj = 0; jj < npair; ++jj) {
    const int j0 = 2*jj;
    __syncthreads();
    *(u16x8*)&Ks[0][srow][scol] = rk[0];
    *(u16x8*)&Vs[0][srow][scol] = rv[0];
    if (j0 + 1 < nkv) {
      *(u16x8*)&Ks[1][srow][scol] = rk[1];
      *(u16x8*)&Vs[1][srow][scol] = rv[1];
    }
    __syncthreads();
    if (jj + 1 < npair) {
      const int jn = 2*(jj + 1);
      rk[0] = *(const u16x8*)(Kbase + (size_t)(jn*64 + srow) * 2048 + scol);
      rv[0] = *(const u16x8*)(Vtbase + (size_t)srow * TT + jn*64 + scol);
      if (jn + 1 < nkv) {
        rk[1] = *(const u16x8*)(Kbase + (size_t)((jn+1)*64 + srow) * 2048 + scol);
        rv[1] = *(const u16x8*)(Vtbase + (size_t)srow * TT + (jn+1)*64 + scol);
      }
    }
    const int j = j0 + hi;
    const int kv0 = j * 64;
    if (j >= nkv || kv0 > qw0 + 15) continue;   // no unmasked cols for this wave

    // S^T = K Q^T: lane holds s[nj][r] = S[q = qw0+c][kv = kv0 + nj*16 + 4g + r]
    f32x4 s[4] = {};
    __builtin_amdgcn_s_setprio(1);
#pragma unroll
    for (int ks = 0; ks < 2; ++ks) {
      const int kc = ks*32 + g*8;
      FragU kf[4];
#pragma unroll
      for (int nj = 0; nj < 4; ++nj)
        kf[nj].u = *(const u16x8*)&Ks[hi][nj*16 + c][kc];
#pragma unroll
      for (int nj = 0; nj < 4; ++nj)
        s[nj] = __builtin_amdgcn_mfma_f32_16x16x32_bf16(kf[nj].b, qf[ks].b, s[nj], 0, 0, 0);
    }
    __builtin_amdgcn_s_setprio(0);

    const bool full = (kv0 + 63 <= qw0);
    const int q = qw0 + c;
    float vmax = -1e30f;
#pragma unroll
    for (int nj = 0; nj < 4; ++nj)
#pragma unroll
      for (int r = 0; r < 4; ++r) {
        float xv = s[nj][r];
        if (!full) {
          if (kv0 + nj*16 + 4*g + r > q) xv = -1e30f;
        }
        s[nj][r] = xv;
        vmax = fmaxf(vmax, xv);
      }

    // ballot-guarded defer-max: common path = 1 vote
    if (__any(vmax > m_run + 8.f)) {
      float vm = vmax;
      vm = fmaxf(vm, __shfl_xor(vm, 1));
      vm = fmaxf(vm, __shfl_xor(vm, 2));
      vm = fmaxf(vm, __shfl_xor(vm, 4));
      vm = fmaxf(vm, __shfl_xor(vm, 8));
      vm = fmaxf(vm, __shfl_xor(vm, 16));
      vm = fmaxf(vm, __shfl_xor(vm, 32));
      float f = exp2f(m_run - vm);   // 0 on first computed tile
      l_part *= f;
#pragma unroll
      for (int dj = 0; dj < 4; ++dj)
#pragma unroll
        for (int i = 0; i < 4; ++i) oacc[dj][i] *= f;
      m_run = vm;
    }

    // P = exp2(S - m), packed directly into PV A-fragments
    FragU pa[2];
    float psum = 0.f;
#pragma unroll
    for (int nj = 0; nj < 4; ++nj)
#pragma unroll
      for (int r = 0; r < 4; ++r) {
        float p = exp2f(s[nj][r] - m_run);
        psum += p;
        BfU cv; cv.h = (__bf16)p;
        pa[nj >> 1].u[(nj & 1) * 4 + r] = cv.u;
      }
    l_part += psum;

    // O += P @ V : B-operand from Vs rows (V^T), kv order matching the swapped layout
    __builtin_amdgcn_s_setprio(1);
#pragma unroll
    for (int ks = 0; ks < 2; ++ks) {
#pragma unroll
      for (int dj = 0; dj < 4; ++dj) {
        const u16* vrow = &Vs[hi][dj*16 + c][ks*32 + 4*g];
        u16x4 lo4 = *(const u16x4*)vrow;
        u16x4 hi4 = *(const u16x4*)(vrow + 16);
        FragU vf;
#pragma unroll
        for (int e = 0; e < 4; ++e) { vf.u[e] = lo4[e]; vf.u[4+e] = hi4[e]; }
        oacc[dj] = __builtin_amdgcn_mfma_f32_16x16x32_bf16(pa[ks].b, vf.b, oacc[dj], 0, 0, 0);
      }
    }
    __builtin_amdgcn_s_setprio(0);
  }

  // ---- merge lo/hi partials ----
  __syncthreads();
  // reduce l over the 4 lane-groups (same q-row set); lane c then holds l(row c)
  l_part += __shfl_xor(l_part, 16);
  l_part += __shfl_xor(l_part, 32);

  float* mO = (float*)&Ks[0][0][0];   // [4][16][66] f32 = 16.9 KB (fits in Ks, 18 KB)
  float* mL = (float*)&Vs[0][0][0];   // [4][16] l1 + [4] m1

  if (hi) {
#pragma unroll
    for (int i = 0; i < 4; ++i) {
      int row = 4*g + i;
#pragma unroll
      for (int dj = 0; dj < 4; ++dj)
        mO[((size_t)(ws_*16 + row))*66 + dj*16 + c] = oacc[dj][i];
    }
    if (lane < 16) mL[ws_*16 + lane] = l_part;
    if (lane == 0) mL[64 + ws_] = m_run;
  }
  __syncthreads();
  if (!hi) {
    float m1 = mL[64 + ws_];
    float l1 = mL[ws_*16 + c];
    float mN = fmaxf(m_run, m1);
    float f0 = exp2f(m_run - mN);   // wave-uniform
    float f1 = exp2f(m1 - mN);
    float lm = l_part * f0 + l1 * f1;
    u16* Ob = O + ((size_t)(b*TT) + qw0) * EE + h*DD;
#pragma unroll
    for (int i = 0; i < 4; ++i) {
      int row = 4*g + i;
      float li = __shfl(lm, row);   // lane 'row' holds c = row
      float inv = 1.f / li;
#pragma unroll
      for (int dj = 0; dj < 4; ++dj) {
        float o1 = mO[((size_t)(ws_*16 + row))*66 + dj*16 + c];
        Ob[(size_t)row * EE + dj*16 + c] = f2bf((oacc[dj][i] * f0 + o1 * f1) * inv);
      }
    }
  }
}

// ---------------- launch ----------------
extern "C" void kernel_launch(void* const* d_in, const int* in_sizes, int n_in,
                              void* d_out, int out_size, void* d_ws, size_t ws_size,
                              hipStream_t stream) {
  const float* x  = (const float*)d_in[0];
  const float* y  = (const float*)d_in[1];
  // d_in[2] = mask (tril causal; implemented analytically)
  const float* Wq = (const float*)d_in[3];
  const float* bq = (const float*)d_in[4];
  const float* Wk = (const float*)d_in[5];
  const float* bk = (const float*)d_in[6];
  const float* Wv = (const float*)d_in[7];
  const float* bv = (const float*)d_in[8];
  const float* Wo = (const float*)d_in[9];
  const float* bo = (const float*)d_in[10];

  if (ws_size < (size_t)67108864) return;  // need 64 MiB scratch

  char* ws = (char*)d_ws;
  u16* Wqt  = (u16*)(ws + 0);          // [1024][1024] bf16, 2 MiB
  u16* Wkvt = (u16*)(ws + 2097152);    // [2048][1024] bf16, 4 MiB ([Wk^T | Wv^T] rows)
  u16* Wot  = (u16*)(ws + 6291456);    // [1024][1024] bf16, 2 MiB
  u16* Qb   = (u16*)(ws + 8388608);    // [4096][1024] bf16, 8 MiB
  u16* KVb  = (u16*)(ws + 16777216);   // [4096][2048] bf16, 16 MiB ([K | V] cols)
  u16* Vtb  = (u16*)(ws + 33554432);   // [2][16][64][2048] bf16, 8 MiB
  u16* Atb  = (u16*)(ws + 41943040);   // [4096][1024] bf16, 8 MiB
  u16* xb   = (u16*)(ws + 50331648);   // [4096][1024] bf16, 8 MiB
  u16* yb   = (u16*)(ws + 58720256);   // [4096][1024] bf16, 8 MiB

  const float c1 = 0.125f * 1.44269504088896340736f;  // scale * log2(e), folded into Q

  cvt_xy<<<4096, 256, 0, stream>>>(x, y, xb, yb);
  wt_cvt4<<<dim3(16,16,4), 256, 0, stream>>>(Wq, Wk, Wv, Wo,
                                             Wqt, Wkvt, Wkvt + (size_t)1024*EE, Wot);
  gemm_qkv<<<1536, 256, 0, stream>>>(xb, yb, Wqt, Wkvt, bq, bk, bv, Qb, KVb, c1);
  transpose_v<<<dim3(32,16,2), 256, 0, stream>>>(KVb, Vtb);
  attn<<<1024, 512, 0, stream>>>(Qb, KVb, Vtb, Atb);
  gemm_o<<<512, 256, 0, stream>>>(Atb, Wot, bo, (float*)d_out);
}

// Round 12
// 119.302 us; speedup vs baseline: 1.6760x; 1.0664x over previous
//
#include <hip/hip_runtime.h>
#include <stdint.h>

#define BB 2
#define TT 2048
#define EE 1024
#define HH 16
#define DD 64
#define MM (BB*TT)   // 4096 rows

typedef unsigned short u16;
typedef __attribute__((ext_vector_type(4))) float f32x4;
typedef __attribute__((ext_vector_type(8))) __bf16 bf16x8;
typedef __attribute__((ext_vector_type(8))) u16 u16x8;
typedef __attribute__((ext_vector_type(4))) u16 u16x4;

union FragU { u16x8 u; bf16x8 b; };
union BfU { __bf16 h; u16 u; };

__device__ __forceinline__ u16 f2bf(float f) {
  uint32_t u = __float_as_uint(f);
  u += 0x7fffu + ((u >> 16) & 1u);   // RNE (inputs are finite)
  return (u16)(u >> 16);
}

// ---------------- prep: f32->bf16 convert of x,y (blocks 0..4095) + weight transposes ----------------
__global__ __launch_bounds__(256) void prep(const float* __restrict__ x, const float* __restrict__ y,
                                            const float* __restrict__ Wq, const float* __restrict__ Wk,
                                            const float* __restrict__ Wv, const float* __restrict__ Wo,
                                            u16* __restrict__ xb, u16* __restrict__ yb,
                                            u16* __restrict__ Wqt, u16* __restrict__ Wkvt,
                                            u16* __restrict__ Wot) {
  __shared__ alignas(16) float tile[64][65];
  int bi = blockIdx.x, t = threadIdx.x;
  if (bi < 4096) {
    const float* src = (bi < 2048) ? x : y;
    u16* dst = (bi < 2048) ? xb : yb;
    int i = (bi & 2047) * 256 + t;
    const f32x4* s4 = (const f32x4*)src;
    f32x4 a = s4[2*i], b = s4[2*i+1];
    u16x8 o;
    o[0]=f2bf(a[0]); o[1]=f2bf(a[1]); o[2]=f2bf(a[2]); o[3]=f2bf(a[3]);
    o[4]=f2bf(b[0]); o[5]=f2bf(b[1]); o[6]=f2bf(b[2]); o[7]=f2bf(b[3]);
    ((u16x8*)dst)[i] = o;
    return;
  }
  int wi = bi - 4096;            // 0..1023
  int z = wi >> 8;               // which weight
  const float* W; u16* Tp;
  switch (z) {
    case 0: W = Wq; Tp = Wqt; break;
    case 1: W = Wk; Tp = Wkvt; break;
    case 2: W = Wv; Tp = Wkvt + (size_t)1024*EE; break;
    default: W = Wo; Tp = Wot; break;
  }
  int r8 = wi & 255;
  int n0 = (r8 & 15) * 64, k0 = (r8 >> 4) * 64;
#pragma unroll
  for (int i = 0; i < 16; ++i) {
    int idx = i*256 + t; int r = idx >> 6, c = idx & 63;
    tile[r][c] = W[(size_t)(k0 + r) * EE + n0 + c];
  }
  __syncthreads();
#pragma unroll
  for (int i = 0; i < 16; ++i) {
    int idx = i*256 + t; int rn = idx >> 6, ck = idx & 63;
    Tp[(size_t)(n0 + rn) * EE + k0 + ck] = f2bf(tile[ck][rn]);
  }
}

// ---------------- GEMM body: C[M][N] = (A @ Bt^T + bias) * oscale ----------------
// 64x128 tile, BK=64, 4 waves (2x2: 32-row x 64-col quadrants), 16x16x32 bf16 MFMA.
// EPI: 0 = bf16 row-major, 1 = f32 row-major, 2 = V^T k-slot-permuted bf16 (for attn PV)
template <int EPI>
__device__ __forceinline__ void gemm_body(const u16* __restrict__ A, const u16* __restrict__ Bt,
                                          const float* __restrict__ bias, void* __restrict__ Cout,
                                          int N, int K, float oscale, int bm, int bn,
                                          u16 (*As)[72], u16 (*Bs)[72]) {
  const int t = threadIdx.x;
  const int lane = t & 63, wave = t >> 6;
  const int wr = wave >> 1, wc = wave & 1;

  f32x4 acc[2][4] = {};

  const int srow = t >> 3;            // 0..31
  const int scol = (t & 7) * 8;       // elem col 0..56
  const u16* Ag = A + (size_t)(bm * 64) * K;
  const u16* Bg = Bt + (size_t)(bn * 128) * K;

  u16x8 ra[2], rb[4];
#pragma unroll
  for (int r = 0; r < 2; ++r)
    ra[r] = *(const u16x8*)(Ag + (size_t)(r*32 + srow) * K + scol);
#pragma unroll
  for (int r = 0; r < 4; ++r)
    rb[r] = *(const u16x8*)(Bg + (size_t)(r*32 + srow) * K + scol);

  const int nk = K / 64;
  for (int kt = 0; kt < nk; ++kt) {
    __syncthreads();
#pragma unroll
    for (int r = 0; r < 2; ++r) *(u16x8*)&As[r*32 + srow][scol] = ra[r];
#pragma unroll
    for (int r = 0; r < 4; ++r) *(u16x8*)&Bs[r*32 + srow][scol] = rb[r];
    __syncthreads();
    if (kt + 1 < nk) {
      const int k0 = (kt + 1) * 64;
#pragma unroll
      for (int r = 0; r < 2; ++r)
        ra[r] = *(const u16x8*)(Ag + (size_t)(r*32 + srow) * K + k0 + scol);
#pragma unroll
      for (int r = 0; r < 4; ++r)
        rb[r] = *(const u16x8*)(Bg + (size_t)(r*32 + srow) * K + k0 + scol);
    }
#pragma unroll
    for (int ks = 0; ks < 2; ++ks) {
      const int kc = ks*32 + ((lane >> 4) << 3);
      FragU af[2], bfr[4];
#pragma unroll
      for (int mi = 0; mi < 2; ++mi)
        af[mi].u = *(const u16x8*)&As[wr*32 + mi*16 + (lane & 15)][kc];
#pragma unroll
      for (int nj = 0; nj < 4; ++nj)
        bfr[nj].u = *(const u16x8*)&Bs[wc*64 + nj*16 + (lane & 15)][kc];
#pragma unroll
      for (int mi = 0; mi < 2; ++mi)
#pragma unroll
        for (int nj = 0; nj < 4; ++nj)
          acc[mi][nj] = __builtin_amdgcn_mfma_f32_16x16x32_bf16(af[mi].b, bfr[nj].b, acc[mi][nj], 0, 0, 0);
    }
  }

  // epilogue. C/D layout: col=lane&15, row=(lane>>4)*4+reg
  const int cbase = bn*128 + wc*64 + (lane & 15);
  float bv[4];
#pragma unroll
  for (int nj = 0; nj < 4; ++nj) bv[nj] = bias[cbase + nj*16];
#pragma unroll
  for (int mi = 0; mi < 2; ++mi) {
    int row0 = bm*64 + wr*32 + mi*16 + ((lane >> 4) << 2);
    if (EPI == 2) {
      // V^T permuted store: t-position p = 32ks | 8g | 4j2 within each 64-block of t
      int bb = row0 >> 11;
      int tt = row0 & 2047;
      int tb64 = tt & ~63;
      int w6 = tt & 63;            // multiple of 4
      int p = ((w6 >> 5) << 5) | (((w6 >> 2) & 3) << 3) | (((w6 >> 4) & 1) << 2);
#pragma unroll
      for (int nj = 0; nj < 4; ++nj) {
        int cc = cbase + nj*16;
        int hh = cc >> 6, dd = cc & 63;
        u16x4 v;
#pragma unroll
        for (int i = 0; i < 4; ++i) v[i] = f2bf(acc[mi][nj][i] + bv[nj]);
        *(u16x4*)((u16*)Cout + ((size_t)((bb*HH + hh)*DD + dd))*2048 + tb64 + p) = v;
      }
    } else {
#pragma unroll
      for (int i = 0; i < 4; ++i) {
        if (EPI == 1) {
          float* Cp = (float*)Cout + (size_t)(row0 + i) * N + cbase;
#pragma unroll
          for (int nj = 0; nj < 4; ++nj)
            Cp[nj*16] = (acc[mi][nj][i] + bv[nj]) * oscale;
        } else {
          u16* Cp = (u16*)Cout + (size_t)(row0 + i) * N + cbase;
#pragma unroll
          for (int nj = 0; nj < 4; ++nj)
            Cp[nj*16] = f2bf((acc[mi][nj][i] + bv[nj]) * oscale);
        }
      }
    }
  }
}

// Fused Q + K + V projection: flat grid 1536, XCD chunk-swizzled so the 24 blocks
// sharing an A-panel (one bm) land on one XCD. V blocks write Vt directly (permuted).
__global__ __launch_bounds__(256) void gemm_qkv(const u16* __restrict__ xb, const u16* __restrict__ yb,
                                                const u16* __restrict__ Wqt, const u16* __restrict__ Wkvt,
                                                const float* __restrict__ bq, const float* __restrict__ bk,
                                                const float* __restrict__ bv,
                                                u16* __restrict__ Qb, u16* __restrict__ Kb,
                                                u16* __restrict__ Vtb, float c1) {
  __shared__ alignas(16) u16 As[64][72];
  __shared__ alignas(16) u16 Bs[128][72];
  const int i = blockIdx.x;
  const int l = (i & 7) * 192 + (i >> 3);   // XCD chunk swizzle (1536 % 8 == 0)
  const int bm = l / 24, bx = l % 24;
  if (bx < 8)
    gemm_body<0>(xb, Wqt, bq, Qb, 1024, EE, c1, bm, bx, As, Bs);
  else if (bx < 16)
    gemm_body<0>(yb, Wkvt, bk, Kb, 1024, EE, 1.0f, bm, bx - 8, As, Bs);
  else
    gemm_body<2>(yb, Wkvt + (size_t)1024*EE, bv, Vtb, 1024, EE, 1.0f, bm, bx - 16, As, Bs);
}

// Output projection: flat grid 512, XCD chunk-swizzled (8 bm-groups per XCD).
__global__ __launch_bounds__(256) void gemm_o(const u16* __restrict__ Atb, const u16* __restrict__ Wot,
                                              const float* __restrict__ bo, float* __restrict__ out) {
  __shared__ alignas(16) u16 As[64][72];
  __shared__ alignas(16) u16 Bs[128][72];
  const int i = blockIdx.x;
  const int l = (i & 7) * 64 + (i >> 3);
  const int bm = l / 8, bn = l % 8;
  gemm_body<1>(Atb, Wot, bo, out, 1024, EE, 1.0f, bm, bn, As, Bs);
}

// ---------------- causal flash attention (split-KV, 8 waves, swapped-QK^T) ----------------
// Block = 512 thr = 8 waves over 64 q-rows: waves 0-3 (lo) compute even kv tiles,
// waves 4-7 (hi) odd kv tiles of the same rows; (m,l,O) partials merged via LDS at end.
// Grid = 1024 blocks, LPT-ordered (qt = 31-(i>>5)). Q pre-scaled by scale*log2(e).
// Vt global layout is k-slot-permuted -> PV fragments are plain b128 LDS reads.
__global__ __launch_bounds__(512, 4) void attn(const u16* __restrict__ Q, const u16* __restrict__ Kb,
                                               const u16* __restrict__ Vt, u16* __restrict__ O) {
  const int i0 = blockIdx.x;
  const int qt = 31 - (i0 >> 5);
  const int bh = i0 & 31;
  const int b = bh >> 4, h = bh & 15;

  const int t = threadIdx.x, lane = t & 63, w = t >> 6;
  const int ws_ = w & 3;            // q sub-block 0..3
  const int hi = w >> 2;            // 0: even tiles, 1: odd tiles
  const int g = lane >> 4, c = lane & 15;
  __shared__ alignas(16) u16 Ks[2][64][72];
  __shared__ alignas(16) u16 Vs[2][64][72];

  const int qw0 = qt * 64 + ws_ * 16;         // 16 q-rows per wave

  // hoist Q fragments (B-operand): row qw0 + c, d = ks*32 + g*8 + 0..7
  FragU qf[2];
  const u16* Qbase = Q + ((size_t)(b*TT) + qw0) * EE + h*DD;
#pragma unroll
  for (int ks = 0; ks < 2; ++ks)
    qf[ks].u = *(const u16x8*)(Qbase + (size_t)c * EE + ks*32 + g*8);

  f32x4 oacc[4] = {};
  float l_part = 0.f;
  float m_run = -1e30f;

  const u16* Kbase = Kb + (size_t)(b*TT) * 1024 + h*DD;
  const u16* Vtbase = Vt + (size_t)(b*HH + h) * DD * 2048;

  const int nkv = qt + 1;
  const int npair = (nkv + 1) >> 1;

  // staging: 512 threads, one u16x8 per tile each (4 tiles/pair: K-even,V-even,K-odd,V-odd)
  const int srow = t >> 3;          // 0..63
  const int scol = (t & 7) * 8;     // u16 col

  u16x8 rk[2], rv[2];
  rk[0] = *(const u16x8*)(Kbase + (size_t)srow * 1024 + scol);
  rv[0] = *(const u16x8*)(Vtbase + (size_t)srow * 2048 + scol);
  if (1 < nkv) {
    rk[1] = *(const u16x8*)(Kbase + (size_t)(64 + srow) * 1024 + scol);
    rv[1] = *(const u16x8*)(Vtbase + (size_t)srow * 2048 + 64 + scol);
  }

  for (int jj = 0; jj < npair; ++jj) {
    const int j0 = 2*jj;
    __syncthreads();
    *(u16x8*)&Ks[0][srow][scol] = rk[0];
    *(u16x8*)&Vs[0][srow][scol] = rv[0];
    if (j0 + 1 < nkv) {
      *(u16x8*)&Ks[1][srow][scol] = rk[1];
      *(u16x8*)&Vs[1][srow][scol] = rv[1];
    }
    __syncthreads();
    if (jj + 1 < npair) {
      const int jn = 2*(jj + 1);
      rk[0] = *(const u16x8*)(Kbase + (size_t)(jn*64 + srow) * 1024 + scol);
      rv[0] = *(const u16x8*)(Vtbase + (size_t)srow * 2048 + jn*64 + scol);
      if (jn + 1 < nkv) {
        rk[1] = *(const u16x8*)(Kbase + (size_t)((jn+1)*64 + srow) * 1024 + scol);
        rv[1] = *(const u16x8*)(Vtbase + (size_t)srow * 2048 + (jn+1)*64 + scol);
      }
    }
    const int j = j0 + hi;
    const int kv0 = j * 64;
    if (j >= nkv || kv0 > qw0 + 15) continue;   // no unmasked cols for this wave

    // S^T = K Q^T: lane holds s[nj][r] = S[q = qw0+c][kv = kv0 + nj*16 + 4g + r]
    f32x4 s[4] = {};
    __builtin_amdgcn_s_setprio(1);
#pragma unroll
    for (int ks = 0; ks < 2; ++ks) {
      const int kc = ks*32 + g*8;
      FragU kf[4];
#pragma unroll
      for (int nj = 0; nj < 4; ++nj)
        kf[nj].u = *(const u16x8*)&Ks[hi][nj*16 + c][kc];
#pragma unroll
      for (int nj = 0; nj < 4; ++nj)
        s[nj] = __builtin_amdgcn_mfma_f32_16x16x32_bf16(kf[nj].b, qf[ks].b, s[nj], 0, 0, 0);
    }
    __builtin_amdgcn_s_setprio(0);

    const bool full = (kv0 + 63 <= qw0);
    const int q = qw0 + c;
    float vmax = -1e30f;
#pragma unroll
    for (int nj = 0; nj < 4; ++nj)
#pragma unroll
      for (int r = 0; r < 4; ++r) {
        float xv = s[nj][r];
        if (!full) {
          if (kv0 + nj*16 + 4*g + r > q) xv = -1e30f;
        }
        s[nj][r] = xv;
        vmax = fmaxf(vmax, xv);
      }

    // ballot-guarded defer-max: common path = 1 vote
    if (__any(vmax > m_run + 8.f)) {
      float vm = vmax;
      vm = fmaxf(vm, __shfl_xor(vm, 1));
      vm = fmaxf(vm, __shfl_xor(vm, 2));
      vm = fmaxf(vm, __shfl_xor(vm, 4));
      vm = fmaxf(vm, __shfl_xor(vm, 8));
      vm = fmaxf(vm, __shfl_xor(vm, 16));
      vm = fmaxf(vm, __shfl_xor(vm, 32));
      float f = exp2f(m_run - vm);   // 0 on first computed tile
      l_part *= f;
#pragma unroll
      for (int dj = 0; dj < 4; ++dj)
#pragma unroll
        for (int i = 0; i < 4; ++i) oacc[dj][i] *= f;
      m_run = vm;
    }

    // P = exp2(S - m), packed directly into PV A-fragments
    FragU pa[2];
    float psum = 0.f;
#pragma unroll
    for (int nj = 0; nj < 4; ++nj)
#pragma unroll
      for (int r = 0; r < 4; ++r) {
        float p = exp2f(s[nj][r] - m_run);
        psum += p;
        BfU cv; cv.h = (__bf16)p;
        pa[nj >> 1].u[(nj & 1) * 4 + r] = cv.u;
      }
    l_part += psum;

    // O += P @ V : B-operand = plain b128 from permuted Vs tile
    __builtin_amdgcn_s_setprio(1);
#pragma unroll
    for (int ks = 0; ks < 2; ++ks) {
#pragma unroll
      for (int dj = 0; dj < 4; ++dj) {
        FragU vf;
        vf.u = *(const u16x8*)&Vs[hi][dj*16 + c][ks*32 + g*8];
        oacc[dj] = __builtin_amdgcn_mfma_f32_16x16x32_bf16(pa[ks].b, vf.b, oacc[dj], 0, 0, 0);
      }
    }
    __builtin_amdgcn_s_setprio(0);
  }

  // ---- merge lo/hi partials ----
  __syncthreads();
  // reduce l over the 4 lane-groups (same q-row set); lane c then holds l(row c)
  l_part += __shfl_xor(l_part, 16);
  l_part += __shfl_xor(l_part, 32);

  float* mO = (float*)&Ks[0][0][0];   // [4][16][66] f32 = 16.9 KB (fits in Ks, 18 KB)
  float* mL = (float*)&Vs[0][0][0];   // [4][16] l1 + [4] m1

  if (hi) {
#pragma unroll
    for (int i = 0; i < 4; ++i) {
      int row = 4*g + i;
#pragma unroll
      for (int dj = 0; dj < 4; ++dj)
        mO[((size_t)(ws_*16 + row))*66 + dj*16 + c] = oacc[dj][i];
    }
    if (lane < 16) mL[ws_*16 + lane] = l_part;
    if (lane == 0) mL[64 + ws_] = m_run;
  }
  __syncthreads();
  if (!hi) {
    float m1 = mL[64 + ws_];
    float l1 = mL[ws_*16 + c];
    float mN = fmaxf(m_run, m1);
    float f0 = exp2f(m_run - mN);   // wave-uniform
    float f1 = exp2f(m1 - mN);
    float lm = l_part * f0 + l1 * f1;
    u16* Ob = O + ((size_t)(b*TT) + qw0) * EE + h*DD;
#pragma unroll
    for (int i = 0; i < 4; ++i) {
      int row = 4*g + i;
      float li = __shfl(lm, row);   // lane 'row' holds c = row
      float inv = 1.f / li;
#pragma unroll
      for (int dj = 0; dj < 4; ++dj) {
        float o1 = mO[((size_t)(ws_*16 + row))*66 + dj*16 + c];
        Ob[(size_t)row * EE + dj*16 + c] = f2bf((oacc[dj][i] * f0 + o1 * f1) * inv);
      }
    }
  }
}

// ---------------- launch ----------------
extern "C" void kernel_launch(void* const* d_in, const int* in_sizes, int n_in,
                              void* d_out, int out_size, void* d_ws, size_t ws_size,
                              hipStream_t stream) {
  const float* x  = (const float*)d_in[0];
  const float* y  = (const float*)d_in[1];
  // d_in[2] = mask (tril causal; implemented analytically)
  const float* Wq = (const float*)d_in[3];
  const float* bq = (const float*)d_in[4];
  const float* Wk = (const float*)d_in[5];
  const float* bk = (const float*)d_in[6];
  const float* Wv = (const float*)d_in[7];
  const float* bv = (const float*)d_in[8];
  const float* Wo = (const float*)d_in[9];
  const float* bo = (const float*)d_in[10];

  if (ws_size < (size_t)58720256) return;  // need 56 MiB scratch

  char* ws = (char*)d_ws;
  u16* Wqt  = (u16*)(ws + 0);          // [1024][1024] bf16, 2 MiB
  u16* Wkvt = (u16*)(ws + 2097152);    // [2048][1024] bf16, 4 MiB ([Wk^T | Wv^T] rows)
  u16* Wot  = (u16*)(ws + 6291456);    // [1024][1024] bf16, 2 MiB
  u16* Qb   = (u16*)(ws + 8388608);    // [4096][1024] bf16, 8 MiB
  u16* Kb   = (u16*)(ws + 16777216);   // [4096][1024] bf16, 8 MiB
  u16* Vtb  = (u16*)(ws + 25165824);   // [2][16][64][2048] bf16 (k-slot permuted), 8 MiB
  u16* Atb  = (u16*)(ws + 33554432);   // [4096][1024] bf16, 8 MiB
  u16* xb   = (u16*)(ws + 41943040);   // [4096][1024] bf16, 8 MiB
  u16* yb   = (u16*)(ws + 50331648);   // [4096][1024] bf16, 8 MiB

  const float c1 = 0.125f * 1.44269504088896340736f;  // scale * log2(e), folded into Q

  prep<<<5120, 256, 0, stream>>>(x, y, Wq, Wk, Wv, Wo, xb, yb, Wqt, Wkvt, Wot);
  gemm_qkv<<<1536, 256, 0, stream>>>(xb, yb, Wqt, Wkvt, bq, bk, bv, Qb, Kb, Vtb, c1);
  attn<<<1024, 512, 0, stream>>>(Qb, Kb, Vtb, Atb);
  gemm_o<<<512, 256, 0, stream>>>(Atb, Wot, bo, (float*)d_out);
}

// Round 13
// 117.111 us; speedup vs baseline: 1.7074x; 1.0187x over previous
//
#include <hip/hip_runtime.h>
#include <stdint.h>

#define BB 2
#define TT 2048
#define EE 1024
#define HH 16
#define DD 64
#define MM (BB*TT)   // 4096 rows

typedef unsigned short u16;
typedef __attribute__((ext_vector_type(4))) float f32x4;
typedef __attribute__((ext_vector_type(8))) __bf16 bf16x8;
typedef __attribute__((ext_vector_type(8))) u16 u16x8;
typedef __attribute__((ext_vector_type(4))) u16 u16x4;

union FragU { u16x8 u; bf16x8 b; };
union BfU { __bf16 h; u16 u; };

__device__ __forceinline__ u16 f2bf(float f) {
  uint32_t u = __float_as_uint(f);
  u += 0x7fffu + ((u >> 16) & 1u);   // RNE (inputs are finite)
  return (u16)(u >> 16);
}

// ---------------- prep: f32->bf16 convert of x,y (blocks 0..4095) + weight transposes ----------------
__global__ __launch_bounds__(256) void prep(const float* __restrict__ x, const float* __restrict__ y,
                                            const float* __restrict__ Wq, const float* __restrict__ Wk,
                                            const float* __restrict__ Wv, const float* __restrict__ Wo,
                                            u16* __restrict__ xb, u16* __restrict__ yb,
                                            u16* __restrict__ Wqt, u16* __restrict__ Wkvt,
                                            u16* __restrict__ Wot) {
  __shared__ alignas(16) float tile[64][65];
  int bi = blockIdx.x, t = threadIdx.x;
  if (bi < 4096) {
    const float* src = (bi < 2048) ? x : y;
    u16* dst = (bi < 2048) ? xb : yb;
    int i = (bi & 2047) * 256 + t;
    const f32x4* s4 = (const f32x4*)src;
    f32x4 a = s4[2*i], b = s4[2*i+1];
    u16x8 o;
    o[0]=f2bf(a[0]); o[1]=f2bf(a[1]); o[2]=f2bf(a[2]); o[3]=f2bf(a[3]);
    o[4]=f2bf(b[0]); o[5]=f2bf(b[1]); o[6]=f2bf(b[2]); o[7]=f2bf(b[3]);
    ((u16x8*)dst)[i] = o;
    return;
  }
  int wi = bi - 4096;            // 0..1023
  int z = wi >> 8;               // which weight
  const float* W; u16* Tp;
  switch (z) {
    case 0: W = Wq; Tp = Wqt; break;
    case 1: W = Wk; Tp = Wkvt; break;
    case 2: W = Wv; Tp = Wkvt + (size_t)1024*EE; break;
    default: W = Wo; Tp = Wot; break;
  }
  int r8 = wi & 255;
  int n0 = (r8 & 15) * 64, k0 = (r8 >> 4) * 64;
#pragma unroll
  for (int i = 0; i < 16; ++i) {
    int idx = i*256 + t; int r = idx >> 6, c = idx & 63;
    tile[r][c] = W[(size_t)(k0 + r) * EE + n0 + c];
  }
  __syncthreads();
#pragma unroll
  for (int i = 0; i < 16; ++i) {
    int idx = i*256 + t; int rn = idx >> 6, ck = idx & 63;
    Tp[(size_t)(n0 + rn) * EE + k0 + ck] = f2bf(tile[ck][rn]);
  }
}

// ---------------- GEMM body: C[M][N] = (A @ Bt^T + bias) * oscale ----------------
// 64x128 tile, BK=64, 4 waves (2x2: 32-row x 64-col quadrants), 16x16x32 bf16 MFMA.
// EPI: 0 = bf16 row-major, 1 = f32 row-major, 2 = V^T k-slot-permuted bf16 (for attn PV)
template <int EPI>
__device__ __forceinline__ void gemm_body(const u16* __restrict__ A, const u16* __restrict__ Bt,
                                          const float* __restrict__ bias, void* __restrict__ Cout,
                                          int N, int K, float oscale, int bm, int bn,
                                          u16 (*As)[72], u16 (*Bs)[72]) {
  const int t = threadIdx.x;
  const int lane = t & 63, wave = t >> 6;
  const int wr = wave >> 1, wc = wave & 1;

  f32x4 acc[2][4] = {};

  const int srow = t >> 3;            // 0..31
  const int scol = (t & 7) * 8;       // elem col 0..56
  const u16* Ag = A + (size_t)(bm * 64) * K;
  const u16* Bg = Bt + (size_t)(bn * 128) * K;

  u16x8 ra[2], rb[4];
#pragma unroll
  for (int r = 0; r < 2; ++r)
    ra[r] = *(const u16x8*)(Ag + (size_t)(r*32 + srow) * K + scol);
#pragma unroll
  for (int r = 0; r < 4; ++r)
    rb[r] = *(const u16x8*)(Bg + (size_t)(r*32 + srow) * K + scol);

  const int nk = K / 64;
  for (int kt = 0; kt < nk; ++kt) {
    __syncthreads();
#pragma unroll
    for (int r = 0; r < 2; ++r) *(u16x8*)&As[r*32 + srow][scol] = ra[r];
#pragma unroll
    for (int r = 0; r < 4; ++r) *(u16x8*)&Bs[r*32 + srow][scol] = rb[r];
    __syncthreads();
    if (kt + 1 < nk) {
      const int k0 = (kt + 1) * 64;
#pragma unroll
      for (int r = 0; r < 2; ++r)
        ra[r] = *(const u16x8*)(Ag + (size_t)(r*32 + srow) * K + k0 + scol);
#pragma unroll
      for (int r = 0; r < 4; ++r)
        rb[r] = *(const u16x8*)(Bg + (size_t)(r*32 + srow) * K + k0 + scol);
    }
#pragma unroll
    for (int ks = 0; ks < 2; ++ks) {
      const int kc = ks*32 + ((lane >> 4) << 3);
      FragU af[2], bfr[4];
#pragma unroll
      for (int mi = 0; mi < 2; ++mi)
        af[mi].u = *(const u16x8*)&As[wr*32 + mi*16 + (lane & 15)][kc];
#pragma unroll
      for (int nj = 0; nj < 4; ++nj)
        bfr[nj].u = *(const u16x8*)&Bs[wc*64 + nj*16 + (lane & 15)][kc];
#pragma unroll
      for (int mi = 0; mi < 2; ++mi)
#pragma unroll
        for (int nj = 0; nj < 4; ++nj)
          acc[mi][nj] = __builtin_amdgcn_mfma_f32_16x16x32_bf16(af[mi].b, bfr[nj].b, acc[mi][nj], 0, 0, 0);
    }
  }

  // epilogue. C/D layout: col=lane&15, row=(lane>>4)*4+reg
  const int cbase = bn*128 + wc*64 + (lane & 15);
  float bv[4];
#pragma unroll
  for (int nj = 0; nj < 4; ++nj) bv[nj] = bias[cbase + nj*16];
#pragma unroll
  for (int mi = 0; mi < 2; ++mi) {
    int row0 = bm*64 + wr*32 + mi*16 + ((lane >> 4) << 2);
    if (EPI == 2) {
      // V^T permuted store: t-position p = 32ks | 8g | 4j2 within each 64-block of t
      int bb = row0 >> 11;
      int tt = row0 & 2047;
      int tb64 = tt & ~63;
      int w6 = tt & 63;            // multiple of 4
      int p = ((w6 >> 5) << 5) | (((w6 >> 2) & 3) << 3) | (((w6 >> 4) & 1) << 2);
#pragma unroll
      for (int nj = 0; nj < 4; ++nj) {
        int cc = cbase + nj*16;
        int hh = cc >> 6, dd = cc & 63;
        u16x4 v;
#pragma unroll
        for (int i = 0; i < 4; ++i) v[i] = f2bf(acc[mi][nj][i] + bv[nj]);
        *(u16x4*)((u16*)Cout + ((size_t)((bb*HH + hh)*DD + dd))*2048 + tb64 + p) = v;
      }
    } else {
#pragma unroll
      for (int i = 0; i < 4; ++i) {
        if (EPI == 1) {
          float* Cp = (float*)Cout + (size_t)(row0 + i) * N + cbase;
#pragma unroll
          for (int nj = 0; nj < 4; ++nj)
            Cp[nj*16] = (acc[mi][nj][i] + bv[nj]) * oscale;
        } else {
          u16* Cp = (u16*)Cout + (size_t)(row0 + i) * N + cbase;
#pragma unroll
          for (int nj = 0; nj < 4; ++nj)
            Cp[nj*16] = f2bf((acc[mi][nj][i] + bv[nj]) * oscale);
        }
      }
    }
  }
}

// Fused Q + K + V projection: flat grid 1536, XCD chunk-swizzled so the 24 blocks
// sharing an A-panel (one bm) land on one XCD. V blocks write Vt directly (permuted).
__global__ __launch_bounds__(256) void gemm_qkv(const u16* __restrict__ xb, const u16* __restrict__ yb,
                                                const u16* __restrict__ Wqt, const u16* __restrict__ Wkvt,
                                                const float* __restrict__ bq, const float* __restrict__ bk,
                                                const float* __restrict__ bv,
                                                u16* __restrict__ Qb, u16* __restrict__ Kb,
                                                u16* __restrict__ Vtb, float c1) {
  __shared__ alignas(16) u16 As[64][72];
  __shared__ alignas(16) u16 Bs[128][72];
  const int i = blockIdx.x;
  const int l = (i & 7) * 192 + (i >> 3);   // XCD chunk swizzle (1536 % 8 == 0)
  const int bm = l / 24, bx = l % 24;
  if (bx < 8)
    gemm_body<0>(xb, Wqt, bq, Qb, 1024, EE, c1, bm, bx, As, Bs);
  else if (bx < 16)
    gemm_body<0>(yb, Wkvt, bk, Kb, 1024, EE, 1.0f, bm, bx - 8, As, Bs);
  else
    gemm_body<2>(yb, Wkvt + (size_t)1024*EE, bv, Vtb, 1024, EE, 1.0f, bm, bx - 16, As, Bs);
}

// Output projection: flat grid 512, XCD chunk-swizzled (8 bm-groups per XCD).
__global__ __launch_bounds__(256) void gemm_o(const u16* __restrict__ Atb, const u16* __restrict__ Wot,
                                              const float* __restrict__ bo, float* __restrict__ out) {
  __shared__ alignas(16) u16 As[64][72];
  __shared__ alignas(16) u16 Bs[128][72];
  const int i = blockIdx.x;
  const int l = (i & 7) * 64 + (i >> 3);
  const int bm = l / 8, bn = l % 8;
  gemm_body<1>(Atb, Wot, bo, out, 1024, EE, 1.0f, bm, bn, As, Bs);
}

// ---------------- causal flash attention (split-KV, 8 waves, swapped-QK^T) ----------------
// Block = 512 thr = 8 waves over 64 q-rows: waves 0-3 (lo) compute even kv tiles,
// waves 4-7 (hi) odd kv tiles of the same rows; (m,l,O) partials merged via LDS at end.
// Balanced qt map: i=(q<<8)|(a<<5)|bh -> qt in {31-a, 16+a, 15-a, a}; with round-robin
// block->CU dispatch each CU's 4 resident blocks sum to nkv = 66 = constant.
// Q pre-scaled by scale*log2(e). Vt is k-slot-permuted -> PV fragments are plain b128.
__global__ __launch_bounds__(512, 4) void attn(const u16* __restrict__ Q, const u16* __restrict__ Kb,
                                               const u16* __restrict__ Vt, u16* __restrict__ O) {
  const int i0 = blockIdx.x;
  const int qq = i0 >> 8, a = (i0 >> 5) & 7, bh = i0 & 31;
  int qt;
  switch (qq) {
    case 0:  qt = 31 - a; break;
    case 1:  qt = 16 + a; break;
    case 2:  qt = 15 - a; break;
    default: qt = a;      break;
  }
  const int b = bh >> 4, h = bh & 15;

  const int t = threadIdx.x, lane = t & 63, w = t >> 6;
  const int ws_ = w & 3;            // q sub-block 0..3
  const int hi = w >> 2;            // 0: even tiles, 1: odd tiles
  const int g = lane >> 4, c = lane & 15;
  __shared__ alignas(16) u16 Ks[2][64][72];
  __shared__ alignas(16) u16 Vs[2][64][72];

  const int qw0 = qt * 64 + ws_ * 16;         // 16 q-rows per wave

  // hoist Q fragments (B-operand): row qw0 + c, d = ks*32 + g*8 + 0..7
  FragU qf[2];
  const u16* Qbase = Q + ((size_t)(b*TT) + qw0) * EE + h*DD;
#pragma unroll
  for (int ks = 0; ks < 2; ++ks)
    qf[ks].u = *(const u16x8*)(Qbase + (size_t)c * EE + ks*32 + g*8);

  f32x4 oacc[4] = {};
  float l_part = 0.f;
  float m_run = -1e30f;

  const u16* Kbase = Kb + (size_t)(b*TT) * 1024 + h*DD;
  const u16* Vtbase = Vt + (size_t)(b*HH + h) * DD * 2048;

  const int nkv = qt + 1;
  const int npair = (nkv + 1) >> 1;

  // staging: 512 threads, one u16x8 per tile each (4 tiles/pair: K-even,V-even,K-odd,V-odd)
  const int srow = t >> 3;          // 0..63
  const int scol = (t & 7) * 8;     // u16 col

  u16x8 rk[2], rv[2];
  rk[0] = *(const u16x8*)(Kbase + (size_t)srow * 1024 + scol);
  rv[0] = *(const u16x8*)(Vtbase + (size_t)srow * 2048 + scol);
  if (1 < nkv) {
    rk[1] = *(const u16x8*)(Kbase + (size_t)(64 + srow) * 1024 + scol);
    rv[1] = *(const u16x8*)(Vtbase + (size_t)srow * 2048 + 64 + scol);
  }

  for (int jj = 0; jj < npair; ++jj) {
    const int j0 = 2*jj;
    __syncthreads();
    *(u16x8*)&Ks[0][srow][scol] = rk[0];
    *(u16x8*)&Vs[0][srow][scol] = rv[0];
    if (j0 + 1 < nkv) {
      *(u16x8*)&Ks[1][srow][scol] = rk[1];
      *(u16x8*)&Vs[1][srow][scol] = rv[1];
    }
    __syncthreads();
    if (jj + 1 < npair) {
      const int jn = 2*(jj + 1);
      rk[0] = *(const u16x8*)(Kbase + (size_t)(jn*64 + srow) * 1024 + scol);
      rv[0] = *(const u16x8*)(Vtbase + (size_t)srow * 2048 + jn*64 + scol);
      if (jn + 1 < nkv) {
        rk[1] = *(const u16x8*)(Kbase + (size_t)((jn+1)*64 + srow) * 1024 + scol);
        rv[1] = *(const u16x8*)(Vtbase + (size_t)srow * 2048 + (jn+1)*64 + scol);
      }
    }
    const int j = j0 + hi;
    const int kv0 = j * 64;
    if (j >= nkv || kv0 > qw0 + 15) continue;   // no unmasked cols for this wave

    // S^T = K Q^T: lane holds s[nj][r] = S[q = qw0+c][kv = kv0 + nj*16 + 4g + r]
    f32x4 s[4] = {};
    __builtin_amdgcn_s_setprio(1);
#pragma unroll
    for (int ks = 0; ks < 2; ++ks) {
      const int kc = ks*32 + g*8;
      FragU kf[4];
#pragma unroll
      for (int nj = 0; nj < 4; ++nj)
        kf[nj].u = *(const u16x8*)&Ks[hi][nj*16 + c][kc];
#pragma unroll
      for (int nj = 0; nj < 4; ++nj)
        s[nj] = __builtin_amdgcn_mfma_f32_16x16x32_bf16(kf[nj].b, qf[ks].b, s[nj], 0, 0, 0);
    }
    __builtin_amdgcn_s_setprio(0);

    const bool full = (kv0 + 63 <= qw0);  // wave-uniform
    float vmax;
    if (full) {
      // fast path: no masking, pure max tree (v_max3-friendly)
      float m0 = fmaxf(fmaxf(s[0][0], s[0][1]), fmaxf(s[0][2], s[0][3]));
      float m1 = fmaxf(fmaxf(s[1][0], s[1][1]), fmaxf(s[1][2], s[1][3]));
      float m2 = fmaxf(fmaxf(s[2][0], s[2][1]), fmaxf(s[2][2], s[2][3]));
      float m3 = fmaxf(fmaxf(s[3][0], s[3][1]), fmaxf(s[3][2], s[3][3]));
      vmax = fmaxf(fmaxf(m0, m1), fmaxf(m2, m3));
    } else {
      const int q = qw0 + c;
      vmax = -1e30f;
#pragma unroll
      for (int nj = 0; nj < 4; ++nj)
#pragma unroll
        for (int r = 0; r < 4; ++r) {
          float xv = s[nj][r];
          if (kv0 + nj*16 + 4*g + r > q) xv = -1e30f;
          s[nj][r] = xv;
          vmax = fmaxf(vmax, xv);
        }
    }

    // ballot-guarded defer-max: common path = 1 vote
    if (__any(vmax > m_run + 8.f)) {
      float vm = vmax;
      vm = fmaxf(vm, __shfl_xor(vm, 1));
      vm = fmaxf(vm, __shfl_xor(vm, 2));
      vm = fmaxf(vm, __shfl_xor(vm, 4));
      vm = fmaxf(vm, __shfl_xor(vm, 8));
      vm = fmaxf(vm, __shfl_xor(vm, 16));
      vm = fmaxf(vm, __shfl_xor(vm, 32));
      float f = exp2f(m_run - vm);   // 0 on first computed tile
      l_part *= f;
#pragma unroll
      for (int dj = 0; dj < 4; ++dj)
#pragma unroll
        for (int i = 0; i < 4; ++i) oacc[dj][i] *= f;
      m_run = vm;
    }

    // P = exp2(S - m), packed directly into PV A-fragments
    FragU pa[2];
    float psum = 0.f;
#pragma unroll
    for (int nj = 0; nj < 4; ++nj)
#pragma unroll
      for (int r = 0; r < 4; ++r) {
        float p = exp2f(s[nj][r] - m_run);
        psum += p;
        BfU cv; cv.h = (__bf16)p;
        pa[nj >> 1].u[(nj & 1) * 4 + r] = cv.u;
      }
    l_part += psum;

    // O += P @ V : B-operand = plain b128 from permuted Vs tile
    __builtin_amdgcn_s_setprio(1);
#pragma unroll
    for (int ks = 0; ks < 2; ++ks) {
#pragma unroll
      for (int dj = 0; dj < 4; ++dj) {
        FragU vf;
        vf.u = *(const u16x8*)&Vs[hi][dj*16 + c][ks*32 + g*8];
        oacc[dj] = __builtin_amdgcn_mfma_f32_16x16x32_bf16(pa[ks].b, vf.b, oacc[dj], 0, 0, 0);
      }
    }
    __builtin_amdgcn_s_setprio(0);
  }

  // ---- merge lo/hi partials ----
  __syncthreads();
  // reduce l over the 4 lane-groups (same q-row set); lane c then holds l(row c)
  l_part += __shfl_xor(l_part, 16);
  l_part += __shfl_xor(l_part, 32);

  float* mO = (float*)&Ks[0][0][0];   // [4][16][66] f32 = 16.9 KB (fits in Ks, 18 KB)
  float* mL = (float*)&Vs[0][0][0];   // [4][16] l1 + [4] m1

  if (hi) {
#pragma unroll
    for (int i = 0; i < 4; ++i) {
      int row = 4*g + i;
#pragma unroll
      for (int dj = 0; dj < 4; ++dj)
        mO[((size_t)(ws_*16 + row))*66 + dj*16 + c] = oacc[dj][i];
    }
    if (lane < 16) mL[ws_*16 + lane] = l_part;
    if (lane == 0) mL[64 + ws_] = m_run;
  }
  __syncthreads();
  if (!hi) {
    float m1 = mL[64 + ws_];
    float l1 = mL[ws_*16 + c];
    float mN = fmaxf(m_run, m1);
    float f0 = exp2f(m_run - mN);   // wave-uniform
    float f1 = exp2f(m1 - mN);
    float lm = l_part * f0 + l1 * f1;
    u16* Ob = O + ((size_t)(b*TT) + qw0) * EE + h*DD;
#pragma unroll
    for (int i = 0; i < 4; ++i) {
      int row = 4*g + i;
      float li = __shfl(lm, row);   // lane 'row' holds c = row
      float inv = 1.f / li;
#pragma unroll
      for (int dj = 0; dj < 4; ++dj) {
        float o1 = mO[((size_t)(ws_*16 + row))*66 + dj*16 + c];
        Ob[(size_t)row * EE + dj*16 + c] = f2bf((oacc[dj][i] * f0 + o1 * f1) * inv);
      }
    }
  }
}

// ---------------- launch ----------------
extern "C" void kernel_launch(void* const* d_in, const int* in_sizes, int n_in,
                              void* d_out, int out_size, void* d_ws, size_t ws_size,
                              hipStream_t stream) {
  const float* x  = (const float*)d_in[0];
  const float* y  = (const float*)d_in[1];
  // d_in[2] = mask (tril causal; implemented analytically)
  const float* Wq = (const float*)d_in[3];
  const float* bq = (const float*)d_in[4];
  const float* Wk = (const float*)d_in[5];
  const float* bk = (const float*)d_in[6];
  const float* Wv = (const float*)d_in[7];
  const float* bv = (const float*)d_in[8];
  const float* Wo = (const float*)d_in[9];
  const float* bo = (const float*)d_in[10];

  if (ws_size < (size_t)58720256) return;  // need 56 MiB scratch

  char* ws = (char*)d_ws;
  u16* Wqt  = (u16*)(ws + 0);          // [1024][1024] bf16, 2 MiB
  u16* Wkvt = (u16*)(ws + 2097152);    // [2048][1024] bf16, 4 MiB ([Wk^T | Wv^T] rows)
  u16* Wot  = (u16*)(ws + 6291456);    // [1024][1024] bf16, 2 MiB
  u16* Qb   = (u16*)(ws + 8388608);    // [4096][1024] bf16, 8 MiB
  u16* Kb   = (u16*)(ws + 16777216);   // [4096][1024] bf16, 8 MiB
  u16* Vtb  = (u16*)(ws + 25165824);   // [2][16][64][2048] bf16 (k-slot permuted), 8 MiB
  u16* Atb  = (u16*)(ws + 33554432);   // [4096][1024] bf16, 8 MiB
  u16* xb   = (u16*)(ws + 41943040);   // [4096][1024] bf16, 8 MiB
  u16* yb   = (u16*)(ws + 50331648);   // [4096][1024] bf16, 8 MiB

  const float c1 = 0.125f * 1.44269504088896340736f;  // scale * log2(e), folded into Q

  prep<<<5120, 256, 0, stream>>>(x, y, Wq, Wk, Wv, Wo, xb, yb, Wqt, Wkvt, Wot);
  gemm_qkv<<<1536, 256, 0, stream>>>(xb, yb, Wqt, Wkvt, bq, bk, bv, Qb, Kb, Vtb, c1);
  attn<<<1024, 512, 0, stream>>>(Qb, Kb, Vtb, Atb);
  gemm_o<<<512, 256, 0, stream>>>(Atb, Wot, bo, (float*)d_out);
}